// Round 2
// baseline (259.841 us; speedup 1.0000x reference)
//
#include <hip/hip_runtime.h>
#include <stdint.h>

#define NN 10000      // nodes
#define NE 160000     // edges
#define NB 16         // batch
// per (b,n) row: CIN*2P = 8*16 = 128 f32, layout [c][t] (t fastest)

typedef __attribute__((ext_vector_type(8))) float f32x8;

// edge_index may arrive as int32 (contract) or raw int64 (reference dtype).
// int64 node ids < 2^32 have all-zero high words; 8 random int32 ids being
// all zero has probability ~1e-32. Deterministic, uniform across threads.
__device__ __forceinline__ int ei_stride(const int* __restrict__ ei) {
    int z = ei[1] | ei[3] | ei[5] | ei[7] | ei[9] | ei[11] | ei[13] | ei[15];
    return (z == 0) ? 2 : 1;
}

__global__ void k_zero(float* deg, int* count) {
    int i = blockIdx.x * blockDim.x + threadIdx.x;
    if (i < NN) { deg[i] = 0.f; count[i] = 0; }
}

__global__ void k_degree(const int* __restrict__ ei, const float* __restrict__ ew,
                         float* deg, int* count) {
    int e = blockIdx.x * blockDim.x + threadIdx.x;
    if (e >= NE) return;
    int stride = ei_stride(ei);
    int d = ei[(size_t)(NE + e) * stride];
    atomicAdd(&deg[d], ew[e]);
    atomicAdd(&count[d], 1);
}

// block 0: exclusive scan of count -> offsets/fillptr; dinv = rsqrt(deg+1)
// block 1: folded weights Mz,Mh (8x32), cz,ch (32), ws = softmax(attention) (16)
__global__ void k_scan_consts(const float* __restrict__ deg, const int* __restrict__ count,
                              float* dinv, int* offsets, int* fillptr,
                              const float* __restrict__ attn,
                              const float* __restrict__ Wcz, const float* __restrict__ bcz,
                              const float* __restrict__ Wlz, const float* __restrict__ blz,
                              const float* __restrict__ Wch, const float* __restrict__ bch,
                              const float* __restrict__ Wlh, const float* __restrict__ blh,
                              float* consts) {
    int tid = threadIdx.x;
    if (blockIdx.x == 1) {
        if (tid < 256) {
            int c = tid >> 5, o = tid & 31;
            float mz = 0.f, mh = 0.f;
            for (int k = 0; k < 32; ++k) {
                mz += Wcz[c * 32 + k] * Wlz[k * 32 + o];   // Wl rows 0..31 (H0 half is zero)
                mh += Wch[c * 32 + k] * Wlh[k * 32 + o];
            }
            consts[tid] = mz;
            consts[256 + tid] = mh;
        }
        if (tid < 32) {
            float cz = blz[tid], ch = blh[tid];
            for (int k = 0; k < 32; ++k) {
                cz += bcz[k] * Wlz[k * 32 + tid];
                ch += bch[k] * Wlh[k * 32 + tid];
            }
            consts[512 + tid] = cz;
            consts[544 + tid] = ch;
        }
        if (tid == 0) {
            float a[16], m = -1e30f, s = 0.f;
            for (int t = 0; t < 16; ++t) { a[t] = attn[t]; m = fmaxf(m, a[t]); }
            for (int t = 0; t < 16; ++t) { a[t] = __expf(a[t] - m); s += a[t]; }
            for (int t = 0; t < 16; ++t) consts[576 + t] = a[t] / s;
        }
        return;
    }
    __shared__ int buf[1024];
    __shared__ int carry;
    if (tid == 0) carry = 0;
    __syncthreads();
    for (int base = 0; base < NN; base += 1024) {
        int i = base + tid;
        int v = (i < NN) ? count[i] : 0;
        buf[tid] = v;
        __syncthreads();
        for (int s = 1; s < 1024; s <<= 1) {
            int t = (tid >= s) ? buf[tid - s] : 0;
            __syncthreads();
            buf[tid] += t;
            __syncthreads();
        }
        int incl = buf[tid];
        int excl = incl - v;
        if (i < NN) { int off = carry + excl; offsets[i] = off; fillptr[i] = off; }
        __syncthreads();
        if (tid == 1023) carry += incl;
        __syncthreads();
    }
    for (int i = tid; i < NN; i += 1024) dinv[i] = rsqrtf(deg[i] + 1.0f);
}

__global__ void k_fill(const int* __restrict__ ei, const float* __restrict__ ew,
                       const float* __restrict__ dinv,
                       int* fillptr, int* csr_src, float* csr_norm) {
    int e = blockIdx.x * blockDim.x + threadIdx.x;
    if (e >= NE) return;
    int stride = ei_stride(ei);
    int s = ei[(size_t)e * stride];
    int d = ei[(size_t)(NE + e) * stride];
    int pos = atomicAdd(&fillptr[d], 1);
    csr_src[pos] = s;
    csr_norm[pos] = dinv[s] * ew[e] * dinv[d];
}

__global__ __launch_bounds__(256)
void k_main(const float* __restrict__ X,
            const int* __restrict__ offsets, const int* __restrict__ count,
            const float* __restrict__ dinv,
            const int* __restrict__ csr_src, const float* __restrict__ csr_norm,
            const float* __restrict__ consts,
            float* __restrict__ out) {
    __shared__ float sAgg[NB * 128];   // [b][c][t] = b*128 + c*16 + t
    __shared__ float sMz[256], sMh[256], sCz[32], sCh[32], sWs[16];
    int tid = threadIdx.x;
    int n = blockIdx.x;

    sMz[tid] = consts[tid];
    sMh[tid] = consts[256 + tid];
    if (tid < 32) { sCz[tid] = consts[512 + tid]; sCh[tid] = consts[544 + tid]; }
    if (tid < 16) sWs[tid] = consts[576 + tid];

    // ---- Phase A: gather agg[b][c][t] over incoming edges + self-loop ----
    int b = tid >> 4;        // 0..15
    int chunk = tid & 15;    // 8 contiguous f32 of the 128-element row
    const f32x8* xv = (const f32x8*)X;   // 16 chunks per (b,n) row
    float dn = dinv[n];
    float selfn = dn * dn;
    float acc[8];
    {
        f32x8 w = xv[((size_t)b * NN + n) * 16 + chunk];
        #pragma unroll
        for (int j = 0; j < 8; ++j) acc[j] = selfn * w[j];
    }
    int off = offsets[n], cnt = count[n];
    for (int e = off; e < off + cnt; ++e) {
        int s = csr_src[e];
        float nrm = csr_norm[e];
        f32x8 w = xv[((size_t)b * NN + s) * 16 + chunk];
        #pragma unroll
        for (int j = 0; j < 8; ++j) acc[j] += nrm * w[j];
    }
    #pragma unroll
    for (int j = 0; j < 8; ++j) sAgg[tid * 8 + j] = acc[j];
    __syncthreads();

    // ---- Phase B: out[b,n,o] = sum_t ws[t]*(1-sigmoid(Uz))*tanh(Uh) ----
    int o = tid & 31, b0 = tid >> 5;   // b0 in 0..7; thread also handles b0+8
    float mz[8], mh[8];
    #pragma unroll
    for (int c = 0; c < 8; ++c) { mz[c] = sMz[c * 32 + o]; mh[c] = sMh[c * 32 + o]; }
    float czo = sCz[o], cho = sCh[o];
    float acc0 = 0.f, acc1 = 0.f;
    #pragma unroll
    for (int t = 0; t < 16; ++t) {
        float uz0 = czo, uh0 = cho, uz1 = czo, uh1 = cho;
        #pragma unroll
        for (int c = 0; c < 8; ++c) {
            float a0 = sAgg[b0 * 128 + c * 16 + t];
            float a1 = sAgg[(b0 + 8) * 128 + c * 16 + t];
            uz0 += a0 * mz[c]; uh0 += a0 * mh[c];
            uz1 += a1 * mz[c]; uh1 += a1 * mh[c];
        }
        float w = sWs[t];
        // (1-sigmoid(x)) = 1/(1+e^x); tanh(x) = 1 - 2/(e^{2x}+1)
        acc0 += w * (1.f / (1.f + __expf(uz0))) * (1.f - 2.f / (__expf(2.f * uh0) + 1.f));
        acc1 += w * (1.f / (1.f + __expf(uz1))) * (1.f - 2.f / (__expf(2.f * uh1) + 1.f));
    }
    out[((size_t)b0 * NN + n) * 32 + o]       = acc0;
    out[((size_t)(b0 + 8) * NN + n) * 32 + o] = acc1;
}

extern "C" void kernel_launch(void* const* d_in, const int* in_sizes, int n_in,
                              void* d_out, int out_size, void* d_ws, size_t ws_size,
                              hipStream_t stream) {
    const float* X    = (const float*)d_in[0];
    const int*   ei   = (const int*)d_in[1];
    const float* ew   = (const float*)d_in[2];
    const float* attn = (const float*)d_in[3];
    const float* Wcz  = (const float*)d_in[4];
    const float* bcz  = (const float*)d_in[5];
    const float* Wlz  = (const float*)d_in[6];
    const float* blz  = (const float*)d_in[7];
    // d_in[8..11] = Wcr,bcr,Wlr,blr — provably unused (R multiplies H0=0)
    const float* Wch  = (const float*)d_in[12];
    const float* bch  = (const float*)d_in[13];
    const float* Wlh  = (const float*)d_in[14];
    const float* blh  = (const float*)d_in[15];
    float* out = (float*)d_out;

    char* p = (char*)d_ws;
    float* deg      = (float*)p; p += NN * 4;
    float* dinv     = (float*)p; p += NN * 4;
    int*   count    = (int*)p;   p += NN * 4;
    int*   offsets  = (int*)p;   p += NN * 4;
    int*   fillptr  = (int*)p;   p += NN * 4;
    int*   csr_src  = (int*)p;   p += NE * 4;
    float* csr_norm = (float*)p; p += NE * 4;
    float* consts   = (float*)p; p += 592 * 4;

    hipLaunchKernelGGL(k_zero, dim3((NN + 255) / 256), dim3(256), 0, stream, deg, count);
    hipLaunchKernelGGL(k_degree, dim3((NE + 255) / 256), dim3(256), 0, stream, ei, ew, deg, count);
    hipLaunchKernelGGL(k_scan_consts, dim3(2), dim3(1024), 0, stream,
                       deg, count, dinv, offsets, fillptr,
                       attn, Wcz, bcz, Wlz, blz, Wch, bch, Wlh, blh, consts);
    hipLaunchKernelGGL(k_fill, dim3((NE + 255) / 256), dim3(256), 0, stream,
                       ei, ew, dinv, fillptr, csr_src, csr_norm);
    hipLaunchKernelGGL(k_main, dim3(NN), dim3(256), 0, stream,
                       X, offsets, count, dinv, csr_src, csr_norm, consts, out);
}

// Round 3
// 223.671 us; speedup vs baseline: 1.1617x; 1.1617x over previous
//
#include <hip/hip_runtime.h>
#include <stdint.h>

#define NN 10000      // nodes
#define NE 160000     // edges
#define NB 16         // batch
// per (b,n) row: CIN*2P = 8*16 = 128 features, layout [c][t] (t fastest)

typedef __attribute__((ext_vector_type(8))) float f32x8;
typedef __attribute__((ext_vector_type(8))) _Float16 h16x8;

// edge_index may arrive as int32 (contract) or raw int64 (reference dtype).
// int64 node ids < 2^32 have all-zero high words.
__device__ __forceinline__ int ei_stride(const int* __restrict__ ei) {
    int z = ei[1] | ei[3] | ei[5] | ei[7] | ei[9] | ei[11] | ei[13] | ei[15];
    return (z == 0) ? 2 : 1;
}

__global__ void k_zero(float* deg, int* count) {
    int i = blockIdx.x * blockDim.x + threadIdx.x;
    if (i < NN) { deg[i] = 0.f; count[i] = 0; }
}

__global__ void k_degree(const int* __restrict__ ei, const float* __restrict__ ew,
                         float* deg, int* count) {
    int e = blockIdx.x * blockDim.x + threadIdx.x;
    if (e >= NE) return;
    int stride = ei_stride(ei);
    int d = ei[(size_t)(NE + e) * stride];
    atomicAdd(&deg[d], ew[e]);
    atomicAdd(&count[d], 1);
}

// block 0: exclusive scan of count -> offsets/fillptr; dinv = rsqrt(deg+1)
// block 1: folded weights Mz,Mh (8x32), cz,ch (32), ws = softmax(attention) (16)
__global__ void k_scan_consts(const float* __restrict__ deg, const int* __restrict__ count,
                              float* dinv, int* offsets, int* fillptr,
                              const float* __restrict__ attn,
                              const float* __restrict__ Wcz, const float* __restrict__ bcz,
                              const float* __restrict__ Wlz, const float* __restrict__ blz,
                              const float* __restrict__ Wch, const float* __restrict__ bch,
                              const float* __restrict__ Wlh, const float* __restrict__ blh,
                              float* consts) {
    int tid = threadIdx.x;
    if (blockIdx.x == 1) {
        if (tid < 256) {
            int c = tid >> 5, o = tid & 31;
            float mz = 0.f, mh = 0.f;
            for (int k = 0; k < 32; ++k) {
                mz += Wcz[c * 32 + k] * Wlz[k * 32 + o];   // Wl rows 0..31 (H0 half is zero)
                mh += Wch[c * 32 + k] * Wlh[k * 32 + o];
            }
            consts[tid] = mz;
            consts[256 + tid] = mh;
        }
        if (tid < 32) {
            float cz = blz[tid], ch = blh[tid];
            for (int k = 0; k < 32; ++k) {
                cz += bcz[k] * Wlz[k * 32 + tid];
                ch += bch[k] * Wlh[k * 32 + tid];
            }
            consts[512 + tid] = cz;
            consts[544 + tid] = ch;
        }
        if (tid == 0) {
            float a[16], m = -1e30f, s = 0.f;
            for (int t = 0; t < 16; ++t) { a[t] = attn[t]; m = fmaxf(m, a[t]); }
            for (int t = 0; t < 16; ++t) { a[t] = __expf(a[t] - m); s += a[t]; }
            for (int t = 0; t < 16; ++t) consts[576 + t] = a[t] / s;
        }
        return;
    }
    __shared__ int buf[1024];
    __shared__ int carry;
    if (tid == 0) carry = 0;
    __syncthreads();
    for (int base = 0; base < NN; base += 1024) {
        int i = base + tid;
        int v = (i < NN) ? count[i] : 0;
        buf[tid] = v;
        __syncthreads();
        for (int s = 1; s < 1024; s <<= 1) {
            int t = (tid >= s) ? buf[tid - s] : 0;
            __syncthreads();
            buf[tid] += t;
            __syncthreads();
        }
        int incl = buf[tid];
        int excl = incl - v;
        if (i < NN) { int off = carry + excl; offsets[i] = off; fillptr[i] = off; }
        __syncthreads();
        if (tid == 1023) carry += incl;
        __syncthreads();
    }
    for (int i = tid; i < NN; i += 1024) dinv[i] = rsqrtf(deg[i] + 1.0f);
}

__global__ void k_fill(const int* __restrict__ ei, const float* __restrict__ ew,
                       const float* __restrict__ dinv,
                       int* fillptr, int* csr_src, float* csr_norm) {
    int e = blockIdx.x * blockDim.x + threadIdx.x;
    if (e >= NE) return;
    int stride = ei_stride(ei);
    int s = ei[(size_t)e * stride];
    int d = ei[(size_t)(NE + e) * stride];
    int pos = atomicAdd(&fillptr[d], 1);
    csr_src[pos] = s;
    csr_norm[pos] = dinv[s] * ew[e] * dinv[d];
}

// X[b][n][128] f32  ->  X2[n][b*128] fp16 (node-major, 4KB/row)
__global__ __launch_bounds__(256)
void k_repack(const float* __restrict__ X, h16x8* __restrict__ X2) {
    int n = blockIdx.x, tid = threadIdx.x;
    int b = tid >> 4, chunk = tid & 15;
    f32x8 w = ((const f32x8*)X)[((size_t)b * NN + n) * 16 + chunk];
    h16x8 h;
    #pragma unroll
    for (int j = 0; j < 8; ++j) h[j] = (_Float16)w[j];
    X2[(size_t)n * 256 + tid] = h;
}

// Shared epilogue: sAgg[b][c][t] -> out
__device__ __forceinline__ void phaseB(const float* sAgg,
                                       const float* sMz, const float* sMh,
                                       const float* sCz, const float* sCh, const float* sWs,
                                       int tid, int n, float* __restrict__ out) {
    int o = tid & 31, b0 = tid >> 5;   // b0 in 0..7; thread also handles b0+8
    float mz[8], mh[8];
    #pragma unroll
    for (int c = 0; c < 8; ++c) { mz[c] = sMz[c * 32 + o]; mh[c] = sMh[c * 32 + o]; }
    float czo = sCz[o], cho = sCh[o];
    float acc0 = 0.f, acc1 = 0.f;
    #pragma unroll
    for (int t = 0; t < 16; ++t) {
        float uz0 = czo, uh0 = cho, uz1 = czo, uh1 = cho;
        #pragma unroll
        for (int c = 0; c < 8; ++c) {
            float a0 = sAgg[b0 * 128 + c * 16 + t];
            float a1 = sAgg[(b0 + 8) * 128 + c * 16 + t];
            uz0 += a0 * mz[c]; uh0 += a0 * mh[c];
            uz1 += a1 * mz[c]; uh1 += a1 * mh[c];
        }
        float w = sWs[t];
        // (1-sigmoid(x)) = 1/(1+e^x); tanh(x) = 1 - 2/(e^{2x}+1)
        acc0 += w * (1.f / (1.f + __expf(uz0))) * (1.f - 2.f / (__expf(2.f * uh0) + 1.f));
        acc1 += w * (1.f / (1.f + __expf(uz1))) * (1.f - 2.f / (__expf(2.f * uh1) + 1.f));
    }
    out[((size_t)b0 * NN + n) * 32 + o]       = acc0;
    out[((size_t)(b0 + 8) * NN + n) * 32 + o] = acc1;
}

// fp16 node-major gather path
__global__ __launch_bounds__(256)
void k_main_h(const h16x8* __restrict__ X2,
              const int* __restrict__ offsets, const int* __restrict__ count,
              const float* __restrict__ dinv,
              const int* __restrict__ csr_src, const float* __restrict__ csr_norm,
              const float* __restrict__ consts,
              float* __restrict__ out) {
    __shared__ float sAgg[NB * 128];
    __shared__ float sMz[256], sMh[256], sCz[32], sCh[32], sWs[16];
    __shared__ int   sSrc[256];
    __shared__ float sNrm[256];
    int tid = threadIdx.x;
    int n = blockIdx.x;

    sMz[tid] = consts[tid];
    sMh[tid] = consts[256 + tid];
    if (tid < 32) { sCz[tid] = consts[512 + tid]; sCh[tid] = consts[544 + tid]; }
    if (tid < 16) sWs[tid] = consts[576 + tid];

    float dn = dinv[n];
    float selfn = dn * dn;
    float acc[8];
    {
        h16x8 w = X2[(size_t)n * 256 + tid];
        #pragma unroll
        for (int j = 0; j < 8; ++j) acc[j] = selfn * (float)w[j];
    }
    int off = offsets[n], cnt = count[n];
    for (int base = 0; base < cnt; base += 256) {
        int m = cnt - base; if (m > 256) m = 256;
        if (tid < m) { sSrc[tid] = csr_src[off + base + tid]; sNrm[tid] = csr_norm[off + base + tid]; }
        __syncthreads();
        for (int e = 0; e < m; ++e) {
            int s = sSrc[e];
            float nrm = sNrm[e];
            h16x8 w = X2[(size_t)s * 256 + tid];
            #pragma unroll
            for (int j = 0; j < 8; ++j) acc[j] += nrm * (float)w[j];  // v_fma_mix_f32
        }
        __syncthreads();
    }
    #pragma unroll
    for (int j = 0; j < 8; ++j) sAgg[tid * 8 + j] = acc[j];
    __syncthreads();
    phaseB(sAgg, sMz, sMh, sCz, sCh, sWs, tid, n, out);
}

// f32 fallback path (proven round-2 kernel) — used only if ws_size is too small
__global__ __launch_bounds__(256)
void k_main_f32(const float* __restrict__ X,
                const int* __restrict__ offsets, const int* __restrict__ count,
                const float* __restrict__ dinv,
                const int* __restrict__ csr_src, const float* __restrict__ csr_norm,
                const float* __restrict__ consts,
                float* __restrict__ out) {
    __shared__ float sAgg[NB * 128];
    __shared__ float sMz[256], sMh[256], sCz[32], sCh[32], sWs[16];
    int tid = threadIdx.x;
    int n = blockIdx.x;

    sMz[tid] = consts[tid];
    sMh[tid] = consts[256 + tid];
    if (tid < 32) { sCz[tid] = consts[512 + tid]; sCh[tid] = consts[544 + tid]; }
    if (tid < 16) sWs[tid] = consts[576 + tid];

    int b = tid >> 4, chunk = tid & 15;
    const f32x8* xv = (const f32x8*)X;
    float dn = dinv[n];
    float selfn = dn * dn;
    float acc[8];
    {
        f32x8 w = xv[((size_t)b * NN + n) * 16 + chunk];
        #pragma unroll
        for (int j = 0; j < 8; ++j) acc[j] = selfn * w[j];
    }
    int off = offsets[n], cnt = count[n];
    for (int e = off; e < off + cnt; ++e) {
        int s = csr_src[e];
        float nrm = csr_norm[e];
        f32x8 w = xv[((size_t)b * NN + s) * 16 + chunk];
        #pragma unroll
        for (int j = 0; j < 8; ++j) acc[j] += nrm * w[j];
    }
    #pragma unroll
    for (int j = 0; j < 8; ++j) sAgg[tid * 8 + j] = acc[j];
    __syncthreads();
    phaseB(sAgg, sMz, sMh, sCz, sCh, sWs, tid, n, out);
}

extern "C" void kernel_launch(void* const* d_in, const int* in_sizes, int n_in,
                              void* d_out, int out_size, void* d_ws, size_t ws_size,
                              hipStream_t stream) {
    const float* X    = (const float*)d_in[0];
    const int*   ei   = (const int*)d_in[1];
    const float* ew   = (const float*)d_in[2];
    const float* attn = (const float*)d_in[3];
    const float* Wcz  = (const float*)d_in[4];
    const float* bcz  = (const float*)d_in[5];
    const float* Wlz  = (const float*)d_in[6];
    const float* blz  = (const float*)d_in[7];
    // d_in[8..11] = Wcr,bcr,Wlr,blr — provably unused (R multiplies H0=0)
    const float* Wch  = (const float*)d_in[12];
    const float* bch  = (const float*)d_in[13];
    const float* Wlh  = (const float*)d_in[14];
    const float* blh  = (const float*)d_in[15];
    float* out = (float*)d_out;

    const size_t x2_bytes = (size_t)NN * 256 * 16;   // 40.96 MB fp16 repack
    const size_t small_bytes = (size_t)NN * 4 * 5 + (size_t)NE * 4 * 2 + 592 * 4;
    bool use_h = (ws_size >= x2_bytes + small_bytes);

    char* p = (char*)d_ws;
    h16x8* X2 = nullptr;
    if (use_h) { X2 = (h16x8*)p; p += x2_bytes; }
    float* deg      = (float*)p; p += NN * 4;
    float* dinv     = (float*)p; p += NN * 4;
    int*   count    = (int*)p;   p += NN * 4;
    int*   offsets  = (int*)p;   p += NN * 4;
    int*   fillptr  = (int*)p;   p += NN * 4;
    int*   csr_src  = (int*)p;   p += NE * 4;
    float* csr_norm = (float*)p; p += NE * 4;
    float* consts   = (float*)p; p += 592 * 4;

    hipLaunchKernelGGL(k_zero, dim3((NN + 255) / 256), dim3(256), 0, stream, deg, count);
    hipLaunchKernelGGL(k_degree, dim3((NE + 255) / 256), dim3(256), 0, stream, ei, ew, deg, count);
    hipLaunchKernelGGL(k_scan_consts, dim3(2), dim3(1024), 0, stream,
                       deg, count, dinv, offsets, fillptr,
                       attn, Wcz, bcz, Wlz, blz, Wch, bch, Wlh, blh, consts);
    hipLaunchKernelGGL(k_fill, dim3((NE + 255) / 256), dim3(256), 0, stream,
                       ei, ew, dinv, fillptr, csr_src, csr_norm);
    if (use_h) {
        hipLaunchKernelGGL(k_repack, dim3(NN), dim3(256), 0, stream, X, X2);
        hipLaunchKernelGGL(k_main_h, dim3(NN), dim3(256), 0, stream,
                           X2, offsets, count, dinv, csr_src, csr_norm, consts, out);
    } else {
        hipLaunchKernelGGL(k_main_f32, dim3(NN), dim3(256), 0, stream,
                           X, offsets, count, dinv, csr_src, csr_norm, consts, out);
    }
}

// Round 4
// 219.285 us; speedup vs baseline: 1.1849x; 1.0200x over previous
//
#include <hip/hip_runtime.h>
#include <stdint.h>

#define NN 10000      // nodes
#define NE 160000     // edges
#define NB 16         // batch
// per (b,n) row: CIN*2P = 8*16 = 128 features, layout [c][t] (t fastest)

typedef __attribute__((ext_vector_type(8))) float f32x8;
typedef __attribute__((ext_vector_type(8))) _Float16 h16x8;

// edge_index may arrive as int32 (contract) or raw int64 (reference dtype).
// int64 node ids < 2^32 have all-zero high words.
__device__ __forceinline__ int ei_stride(const int* __restrict__ ei) {
    int z = ei[1] | ei[3] | ei[5] | ei[7] | ei[9] | ei[11] | ei[13] | ei[15];
    return (z == 0) ? 2 : 1;
}

__global__ void k_zero(float* deg, int* count) {
    int i = blockIdx.x * blockDim.x + threadIdx.x;
    if (i < NN) { deg[i] = 0.f; count[i] = 0; }
}

__global__ void k_degree(const int* __restrict__ ei, const float* __restrict__ ew,
                         float* deg, int* count) {
    int e = blockIdx.x * blockDim.x + threadIdx.x;
    if (e >= NE) return;
    int stride = ei_stride(ei);
    int d = ei[(size_t)(NE + e) * stride];
    atomicAdd(&deg[d], ew[e]);
    atomicAdd(&count[d], 1);
}

// block 0: exclusive scan of count -> offsets/fillptr; dinv = rsqrt(deg+1)
// block 1: folded weights Mz,Mh (8x32), cz,ch (32), ws = softmax(attention) (16)
__global__ void k_scan_consts(const float* __restrict__ deg, const int* __restrict__ count,
                              float* dinv, int* offsets, int* fillptr,
                              const float* __restrict__ attn,
                              const float* __restrict__ Wcz, const float* __restrict__ bcz,
                              const float* __restrict__ Wlz, const float* __restrict__ blz,
                              const float* __restrict__ Wch, const float* __restrict__ bch,
                              const float* __restrict__ Wlh, const float* __restrict__ blh,
                              float* consts) {
    int tid = threadIdx.x;
    if (blockIdx.x == 1) {
        if (tid < 256) {
            int c = tid >> 5, o = tid & 31;
            float mz = 0.f, mh = 0.f;
            for (int k = 0; k < 32; ++k) {
                mz += Wcz[c * 32 + k] * Wlz[k * 32 + o];   // Wl rows 0..31 (H0 half is zero)
                mh += Wch[c * 32 + k] * Wlh[k * 32 + o];
            }
            consts[tid] = mz;
            consts[256 + tid] = mh;
        }
        if (tid < 32) {
            float cz = blz[tid], ch = blh[tid];
            for (int k = 0; k < 32; ++k) {
                cz += bcz[k] * Wlz[k * 32 + tid];
                ch += bch[k] * Wlh[k * 32 + tid];
            }
            consts[512 + tid] = cz;
            consts[544 + tid] = ch;
        }
        if (tid == 0) {
            float a[16], m = -1e30f, s = 0.f;
            for (int t = 0; t < 16; ++t) { a[t] = attn[t]; m = fmaxf(m, a[t]); }
            for (int t = 0; t < 16; ++t) { a[t] = __expf(a[t] - m); s += a[t]; }
            for (int t = 0; t < 16; ++t) consts[576 + t] = a[t] / s;
        }
        return;
    }
    __shared__ int buf[1024];
    __shared__ int carry;
    if (tid == 0) carry = 0;
    __syncthreads();
    for (int base = 0; base < NN; base += 1024) {
        int i = base + tid;
        int v = (i < NN) ? count[i] : 0;
        buf[tid] = v;
        __syncthreads();
        for (int s = 1; s < 1024; s <<= 1) {
            int t = (tid >= s) ? buf[tid - s] : 0;
            __syncthreads();
            buf[tid] += t;
            __syncthreads();
        }
        int incl = buf[tid];
        int excl = incl - v;
        if (i < NN) { int off = carry + excl; offsets[i] = off; fillptr[i] = off; }
        __syncthreads();
        if (tid == 1023) carry += incl;
        __syncthreads();
    }
    for (int i = tid; i < NN; i += 1024) dinv[i] = rsqrtf(deg[i] + 1.0f);
}

__global__ void k_fill(const int* __restrict__ ei, const float* __restrict__ ew,
                       const float* __restrict__ dinv,
                       int* fillptr, int* csr_src, float* csr_norm) {
    int e = blockIdx.x * blockDim.x + threadIdx.x;
    if (e >= NE) return;
    int stride = ei_stride(ei);
    int s = ei[(size_t)e * stride];
    int d = ei[(size_t)(NE + e) * stride];
    int pos = atomicAdd(&fillptr[d], 1);
    csr_src[pos] = s;
    csr_norm[pos] = dinv[s] * ew[e] * dinv[d];
}

// X[b][n][128] f32  ->  X2[n][b*128] fp16 (node-major, 4KB/row), grid-stride
__global__ __launch_bounds__(256)
void k_repack(const float* __restrict__ X, h16x8* __restrict__ X2) {
    const int total = NN * 256;
    for (int i = blockIdx.x * blockDim.x + threadIdx.x; i < total;
         i += gridDim.x * blockDim.x) {
        int n = i >> 8, t = i & 255;
        int b = t >> 4, chunk = t & 15;
        f32x8 w = ((const f32x8*)X)[((size_t)b * NN + n) * 16 + chunk];
        h16x8 h;
        #pragma unroll
        for (int j = 0; j < 8; ++j) h[j] = (_Float16)w[j];
        X2[(size_t)n * 256 + t] = h;
    }
}

// Shared epilogue: sAgg[b][c][t] -> out
__device__ __forceinline__ void phaseB(const float* sAgg,
                                       const float* sMz, const float* sMh,
                                       const float* sCz, const float* sCh, const float* sWs,
                                       int tid, int n, float* __restrict__ out) {
    int o = tid & 31, b0 = tid >> 5;   // b0 in 0..7; thread also handles b0+8
    float mz[8], mh[8];
    #pragma unroll
    for (int c = 0; c < 8; ++c) { mz[c] = sMz[c * 32 + o]; mh[c] = sMh[c * 32 + o]; }
    float czo = sCz[o], cho = sCh[o];
    float acc0 = 0.f, acc1 = 0.f;
    #pragma unroll
    for (int t = 0; t < 16; ++t) {
        float uz0 = czo, uh0 = cho, uz1 = czo, uh1 = cho;
        #pragma unroll
        for (int c = 0; c < 8; ++c) {
            float a0 = sAgg[b0 * 128 + c * 16 + t];
            float a1 = sAgg[(b0 + 8) * 128 + c * 16 + t];
            uz0 += a0 * mz[c]; uh0 += a0 * mh[c];
            uz1 += a1 * mz[c]; uh1 += a1 * mh[c];
        }
        float w = sWs[t];
        // (1-sigmoid(x)) = 1/(1+e^x); tanh(x) = 1 - 2/(e^{2x}+1)
        acc0 += w * (1.f / (1.f + __expf(uz0))) * (1.f - 2.f / (__expf(2.f * uh0) + 1.f));
        acc1 += w * (1.f / (1.f + __expf(uz1))) * (1.f - 2.f / (__expf(2.f * uh1) + 1.f));
    }
    out[((size_t)b0 * NN + n) * 32 + o]       = acc0;
    out[((size_t)(b0 + 8) * NN + n) * 32 + o] = acc1;
}

// fp16 node-major gather path, 8-way software-pipelined loads.
// (src,norm) read directly from global: wave-uniform addresses -> scalar loads,
// keeping the per-edge dependence chain free of LDS/barrier latency.
__global__ __launch_bounds__(256)
void k_main_h(const h16x8* __restrict__ X2,
              const int* __restrict__ offsets, const int* __restrict__ count,
              const float* __restrict__ dinv,
              const int* __restrict__ csr_src, const float* __restrict__ csr_norm,
              const float* __restrict__ consts,
              float* __restrict__ out) {
    __shared__ float sAgg[NB * 128];
    __shared__ float sMz[256], sMh[256], sCz[32], sCh[32], sWs[16];
    int tid = threadIdx.x;
    int n = blockIdx.x;

    sMz[tid] = consts[tid];
    sMh[tid] = consts[256 + tid];
    if (tid < 32) { sCz[tid] = consts[512 + tid]; sCh[tid] = consts[544 + tid]; }
    if (tid < 16) sWs[tid] = consts[576 + tid];

    float dn = dinv[n];
    float selfn = dn * dn;
    float acc[8];
    {
        h16x8 w = X2[(size_t)n * 256 + tid];
        #pragma unroll
        for (int j = 0; j < 8; ++j) acc[j] = selfn * (float)w[j];
    }
    int off = offsets[n], cnt = count[n];
    const int*   sp  = csr_src + off;
    const float* npv = csr_norm + off;
    int e = 0;
    for (; e + 8 <= cnt; e += 8) {
        int   ss[8];
        float nm[8];
        #pragma unroll
        for (int q = 0; q < 8; ++q) { ss[q] = sp[e + q]; nm[q] = npv[e + q]; }
        h16x8 w[8];
        #pragma unroll
        for (int q = 0; q < 8; ++q) w[q] = X2[(size_t)ss[q] * 256 + tid];
        #pragma unroll
        for (int q = 0; q < 8; ++q) {
            #pragma unroll
            for (int j = 0; j < 8; ++j) acc[j] += nm[q] * (float)w[q][j];
        }
    }
    for (; e + 4 <= cnt; e += 4) {
        int   ss[4];
        float nm[4];
        #pragma unroll
        for (int q = 0; q < 4; ++q) { ss[q] = sp[e + q]; nm[q] = npv[e + q]; }
        h16x8 w[4];
        #pragma unroll
        for (int q = 0; q < 4; ++q) w[q] = X2[(size_t)ss[q] * 256 + tid];
        #pragma unroll
        for (int q = 0; q < 4; ++q) {
            #pragma unroll
            for (int j = 0; j < 8; ++j) acc[j] += nm[q] * (float)w[q][j];
        }
    }
    for (; e < cnt; ++e) {
        int s = sp[e];
        float nrm = npv[e];
        h16x8 w = X2[(size_t)s * 256 + tid];
        #pragma unroll
        for (int j = 0; j < 8; ++j) acc[j] += nrm * (float)w[j];
    }
    #pragma unroll
    for (int j = 0; j < 8; ++j) sAgg[tid * 8 + j] = acc[j];
    __syncthreads();
    phaseB(sAgg, sMz, sMh, sCz, sCh, sWs, tid, n, out);
}

// f32 fallback path — used only if ws_size is too small for the fp16 repack
__global__ __launch_bounds__(256)
void k_main_f32(const float* __restrict__ X,
                const int* __restrict__ offsets, const int* __restrict__ count,
                const float* __restrict__ dinv,
                const int* __restrict__ csr_src, const float* __restrict__ csr_norm,
                const float* __restrict__ consts,
                float* __restrict__ out) {
    __shared__ float sAgg[NB * 128];
    __shared__ float sMz[256], sMh[256], sCz[32], sCh[32], sWs[16];
    int tid = threadIdx.x;
    int n = blockIdx.x;

    sMz[tid] = consts[tid];
    sMh[tid] = consts[256 + tid];
    if (tid < 32) { sCz[tid] = consts[512 + tid]; sCh[tid] = consts[544 + tid]; }
    if (tid < 16) sWs[tid] = consts[576 + tid];

    int b = tid >> 4, chunk = tid & 15;
    const f32x8* xv = (const f32x8*)X;
    float dn = dinv[n];
    float selfn = dn * dn;
    float acc[8];
    {
        f32x8 w = xv[((size_t)b * NN + n) * 16 + chunk];
        #pragma unroll
        for (int j = 0; j < 8; ++j) acc[j] = selfn * w[j];
    }
    int off = offsets[n], cnt = count[n];
    for (int e = off; e < off + cnt; ++e) {
        int s = csr_src[e];
        float nrm = csr_norm[e];
        f32x8 w = xv[((size_t)b * NN + s) * 16 + chunk];
        #pragma unroll
        for (int j = 0; j < 8; ++j) acc[j] += nrm * w[j];
    }
    #pragma unroll
    for (int j = 0; j < 8; ++j) sAgg[tid * 8 + j] = acc[j];
    __syncthreads();
    phaseB(sAgg, sMz, sMh, sCz, sCh, sWs, tid, n, out);
}

extern "C" void kernel_launch(void* const* d_in, const int* in_sizes, int n_in,
                              void* d_out, int out_size, void* d_ws, size_t ws_size,
                              hipStream_t stream) {
    const float* X    = (const float*)d_in[0];
    const int*   ei   = (const int*)d_in[1];
    const float* ew   = (const float*)d_in[2];
    const float* attn = (const float*)d_in[3];
    const float* Wcz  = (const float*)d_in[4];
    const float* bcz  = (const float*)d_in[5];
    const float* Wlz  = (const float*)d_in[6];
    const float* blz  = (const float*)d_in[7];
    // d_in[8..11] = Wcr,bcr,Wlr,blr — provably unused (R multiplies H0=0)
    const float* Wch  = (const float*)d_in[12];
    const float* bch  = (const float*)d_in[13];
    const float* Wlh  = (const float*)d_in[14];
    const float* blh  = (const float*)d_in[15];
    float* out = (float*)d_out;

    const size_t x2_bytes = (size_t)NN * 256 * 16;   // 40.96 MB fp16 repack
    const size_t small_bytes = (size_t)NN * 4 * 5 + (size_t)NE * 4 * 2 + 592 * 4;
    bool use_h = (ws_size >= x2_bytes + small_bytes);

    char* p = (char*)d_ws;
    h16x8* X2 = nullptr;
    if (use_h) { X2 = (h16x8*)p; p += x2_bytes; }
    float* deg      = (float*)p; p += NN * 4;
    float* dinv     = (float*)p; p += NN * 4;
    int*   count    = (int*)p;   p += NN * 4;
    int*   offsets  = (int*)p;   p += NN * 4;
    int*   fillptr  = (int*)p;   p += NN * 4;
    int*   csr_src  = (int*)p;   p += NE * 4;
    float* csr_norm = (float*)p; p += NE * 4;
    float* consts   = (float*)p; p += 592 * 4;

    if (use_h) {
        hipLaunchKernelGGL(k_repack, dim3(1280), dim3(256), 0, stream, X, X2);
    }
    hipLaunchKernelGGL(k_zero, dim3((NN + 255) / 256), dim3(256), 0, stream, deg, count);
    hipLaunchKernelGGL(k_degree, dim3((NE + 255) / 256), dim3(256), 0, stream, ei, ew, deg, count);
    hipLaunchKernelGGL(k_scan_consts, dim3(2), dim3(1024), 0, stream,
                       deg, count, dinv, offsets, fillptr,
                       attn, Wcz, bcz, Wlz, blz, Wch, bch, Wlh, blh, consts);
    hipLaunchKernelGGL(k_fill, dim3((NE + 255) / 256), dim3(256), 0, stream,
                       ei, ew, dinv, fillptr, csr_src, csr_norm);
    if (use_h) {
        hipLaunchKernelGGL(k_main_h, dim3(NN), dim3(256), 0, stream,
                           X2, offsets, count, dinv, csr_src, csr_norm, consts, out);
    } else {
        hipLaunchKernelGGL(k_main_f32, dim3(NN), dim3(256), 0, stream,
                           X, offsets, count, dinv, csr_src, csr_norm, consts, out);
    }
}

// Round 5
// 200.971 us; speedup vs baseline: 1.2929x; 1.0911x over previous
//
#include <hip/hip_runtime.h>
#include <stdint.h>

#define NN 10000      // nodes
#define NE 160000     // edges
#define NB 16         // batch
// per (b,n) row: CIN*2P = 8*16 = 128 features, layout [c][t] (t fastest)

typedef __attribute__((ext_vector_type(8))) float f32x8;
typedef __attribute__((ext_vector_type(4))) float f32x4;
typedef __attribute__((ext_vector_type(2))) float f32x2;
typedef __attribute__((ext_vector_type(8))) _Float16 h16x8;

#define AGG_LD 136   // 128 + 8 pad floats per b-row (bank-shift 8 per b)

// edge_index may arrive as int32 (contract) or raw int64 (reference dtype).
// int64 node ids < 2^32 have all-zero high words.
__device__ __forceinline__ int ei_stride(const int* __restrict__ ei) {
    int z = ei[1] | ei[3] | ei[5] | ei[7] | ei[9] | ei[11] | ei[13] | ei[15];
    return (z == 0) ? 2 : 1;
}

__global__ void k_zero(float* deg, int* count) {
    int i = blockIdx.x * blockDim.x + threadIdx.x;
    if (i < NN) { deg[i] = 0.f; count[i] = 0; }
}

__global__ void k_degree(const int* __restrict__ ei, const float* __restrict__ ew,
                         float* deg, int* count) {
    int e = blockIdx.x * blockDim.x + threadIdx.x;
    if (e >= NE) return;
    int stride = ei_stride(ei);
    int d = ei[(size_t)(NE + e) * stride];
    atomicAdd(&deg[d], ew[e]);
    atomicAdd(&count[d], 1);
}

// block 0: exclusive scan of count -> offsets/fillptr; dinv = rsqrt(deg+1)
// block 1: folded weights Mz,Mh (8x32), cz,ch (32), ws = softmax(attention) (16)
__global__ void k_scan_consts(const float* __restrict__ deg, const int* __restrict__ count,
                              float* dinv, int* offsets, int* fillptr,
                              const float* __restrict__ attn,
                              const float* __restrict__ Wcz, const float* __restrict__ bcz,
                              const float* __restrict__ Wlz, const float* __restrict__ blz,
                              const float* __restrict__ Wch, const float* __restrict__ bch,
                              const float* __restrict__ Wlh, const float* __restrict__ blh,
                              float* consts) {
    int tid = threadIdx.x;
    if (blockIdx.x == 1) {
        if (tid < 256) {
            int c = tid >> 5, o = tid & 31;
            float mz = 0.f, mh = 0.f;
            for (int k = 0; k < 32; ++k) {
                mz += Wcz[c * 32 + k] * Wlz[k * 32 + o];   // Wl rows 0..31 (H0 half is zero)
                mh += Wch[c * 32 + k] * Wlh[k * 32 + o];
            }
            consts[tid] = mz;
            consts[256 + tid] = mh;
        }
        if (tid < 32) {
            float cz = blz[tid], ch = blh[tid];
            for (int k = 0; k < 32; ++k) {
                cz += bcz[k] * Wlz[k * 32 + tid];
                ch += bch[k] * Wlh[k * 32 + tid];
            }
            consts[512 + tid] = cz;
            consts[544 + tid] = ch;
        }
        if (tid == 0) {
            float a[16], m = -1e30f, s = 0.f;
            for (int t = 0; t < 16; ++t) { a[t] = attn[t]; m = fmaxf(m, a[t]); }
            for (int t = 0; t < 16; ++t) { a[t] = __expf(a[t] - m); s += a[t]; }
            for (int t = 0; t < 16; ++t) consts[576 + t] = a[t] / s;
        }
        return;
    }
    __shared__ int buf[1024];
    __shared__ int carry;
    if (tid == 0) carry = 0;
    __syncthreads();
    for (int base = 0; base < NN; base += 1024) {
        int i = base + tid;
        int v = (i < NN) ? count[i] : 0;
        buf[tid] = v;
        __syncthreads();
        for (int s = 1; s < 1024; s <<= 1) {
            int t = (tid >= s) ? buf[tid - s] : 0;
            __syncthreads();
            buf[tid] += t;
            __syncthreads();
        }
        int incl = buf[tid];
        int excl = incl - v;
        if (i < NN) { int off = carry + excl; offsets[i] = off; fillptr[i] = off; }
        __syncthreads();
        if (tid == 1023) carry += incl;
        __syncthreads();
    }
    for (int i = tid; i < NN; i += 1024) dinv[i] = rsqrtf(deg[i] + 1.0f);
}

__global__ void k_fill(const int* __restrict__ ei, const float* __restrict__ ew,
                       const float* __restrict__ dinv,
                       int* fillptr, int* csr_src, float* csr_norm) {
    int e = blockIdx.x * blockDim.x + threadIdx.x;
    if (e >= NE) return;
    int stride = ei_stride(ei);
    int s = ei[(size_t)e * stride];
    int d = ei[(size_t)(NE + e) * stride];
    int pos = atomicAdd(&fillptr[d], 1);
    csr_src[pos] = s;
    csr_norm[pos] = dinv[s] * ew[e] * dinv[d];
}

// X[b][n][128] f32  ->  X2[n][b*128] fp16 (node-major, 4KB/row), grid-stride
__global__ __launch_bounds__(256)
void k_repack(const float* __restrict__ X, h16x8* __restrict__ X2) {
    const int total = NN * 256;
    for (int i = blockIdx.x * blockDim.x + threadIdx.x; i < total;
         i += gridDim.x * blockDim.x) {
        int n = i >> 8, t = i & 255;
        int b = t >> 4, chunk = t & 15;
        f32x8 w = ((const f32x8*)X)[((size_t)b * NN + n) * 16 + chunk];
        h16x8 h;
        #pragma unroll
        for (int j = 0; j < 8; ++j) h[j] = (_Float16)w[j];
        X2[(size_t)n * 256 + t] = h;
    }
}

__device__ __forceinline__ float gatefn(float uz, float uh) {
    // (1-sigmoid(uz)) * tanh(uh)
    return (1.f / (1.f + __expf(uz))) * (1.f - 2.f / (__expf(2.f * uh) + 1.f));
}

// fp16 node-major gather + fused transform.
// sAgg layout: [b][tp][c][half] float, row stride AGG_LD (=136, pad kills
// write bank conflicts; reads are broadcast).  tp = t>>1, half = t&1.
__global__ __launch_bounds__(256)
void k_main_h(const h16x8* __restrict__ X2,
              const int* __restrict__ offsets, const int* __restrict__ count,
              const float* __restrict__ dinv,
              const int* __restrict__ csr_src, const float* __restrict__ csr_norm,
              const float* __restrict__ consts,
              float* __restrict__ out) {
    __shared__ float sAgg[NB * AGG_LD];
    __shared__ float sMz[256], sMh[256], sCz[32], sCh[32], sWs[16];
    int tid = threadIdx.x;
    int n = blockIdx.x;

    sMz[tid] = consts[tid];
    sMh[tid] = consts[256 + tid];
    if (tid < 32) { sCz[tid] = consts[512 + tid]; sCh[tid] = consts[544 + tid]; }
    if (tid < 16) sWs[tid] = consts[576 + tid];

    // ---- Phase A: gather ----
    int b = tid >> 4;        // 0..15
    int chunk = tid & 15;    // this thread owns c = chunk>>1, t = (chunk&1)*8 + j
    float dn = dinv[n];
    float selfn = dn * dn;
    float acc[8];
    {
        h16x8 w = X2[(size_t)n * 256 + tid];
        #pragma unroll
        for (int j = 0; j < 8; ++j) acc[j] = selfn * (float)w[j];
    }
    int off = offsets[n], cnt = count[n];
    const int*   sp  = csr_src + off;
    const float* npv = csr_norm + off;
    int e = 0;
    for (; e + 4 <= cnt; e += 4) {
        int   ss[4];
        float nm[4];
        #pragma unroll
        for (int q = 0; q < 4; ++q) { ss[q] = sp[e + q]; nm[q] = npv[e + q]; }
        h16x8 w[4];
        #pragma unroll
        for (int q = 0; q < 4; ++q) w[q] = X2[(size_t)ss[q] * 256 + tid];
        #pragma unroll
        for (int q = 0; q < 4; ++q) {
            #pragma unroll
            for (int j = 0; j < 8; ++j) acc[j] += nm[q] * (float)w[q][j];
        }
    }
    for (; e < cnt; ++e) {
        int s = sp[e];
        float nrm = npv[e];
        h16x8 w = X2[(size_t)s * 256 + tid];
        #pragma unroll
        for (int j = 0; j < 8; ++j) acc[j] += nrm * (float)w[j];
    }
    // store: acc[j] = A[b][c][t=tbase+j] -> sAgg[b*AGG_LD + tp*16 + c*2 + (t&1)]
    {
        int c = chunk >> 1;
        int tpb = (chunk & 1) * 4;           // tp base (t base / 2)
        float* rowp = &sAgg[b * AGG_LD + c * 2];
        #pragma unroll
        for (int k = 0; k < 4; ++k) {
            f32x2 v = {acc[2 * k], acc[2 * k + 1]};
            *(f32x2*)&rowp[(tpb + k) * 16] = v;
        }
    }
    __syncthreads();

    // ---- Phase B: per (b,o): out = sum_t ws[t] * gate(Uz,Uh) ----
    int o = tid & 31, b0 = tid >> 5;   // handles b0 and b0+8
    float mz[8], mh[8];
    #pragma unroll
    for (int c = 0; c < 8; ++c) { mz[c] = sMz[c * 32 + o]; mh[c] = sMh[c * 32 + o]; }
    float czo = sCz[o], cho = sCh[o];
    const f32x4* r0 = (const f32x4*)&sAgg[b0 * AGG_LD];
    const f32x4* r1 = (const f32x4*)&sAgg[(b0 + 8) * AGG_LD];
    f32x2 out0 = {0.f, 0.f}, out1 = {0.f, 0.f};
    #pragma unroll
    for (int tp = 0; tp < 8; ++tp) {
        f32x4 A0[4], A1[4];
        #pragma unroll
        for (int k = 0; k < 4; ++k) { A0[k] = r0[tp * 4 + k]; A1[k] = r1[tp * 4 + k]; }
        f32x2 uz0 = {czo, czo}, uh0 = {cho, cho};
        f32x2 uz1 = {czo, czo}, uh1 = {cho, cho};
        #pragma unroll
        for (int k = 0; k < 4; ++k) {
            f32x2 p0 = A0[k].xy, q0 = A0[k].zw;   // channels 2k, 2k+1 (t-even/odd pairs)
            f32x2 p1 = A1[k].xy, q1 = A1[k].zw;
            float m0 = mz[2 * k], m1 = mz[2 * k + 1];
            float n0 = mh[2 * k], n1 = mh[2 * k + 1];
            uz0 += p0 * m0; uz0 += q0 * m1;
            uh0 += p0 * n0; uh0 += q0 * n1;
            uz1 += p1 * m0; uz1 += q1 * m1;
            uh1 += p1 * n0; uh1 += q1 * n1;
        }
        f32x2 wsp = {sWs[2 * tp], sWs[2 * tp + 1]};
        f32x2 g0, g1;
        g0.x = gatefn(uz0.x, uh0.x); g0.y = gatefn(uz0.y, uh0.y);
        g1.x = gatefn(uz1.x, uh1.x); g1.y = gatefn(uz1.y, uh1.y);
        out0 += wsp * g0;
        out1 += wsp * g1;
    }
    out[((size_t)b0 * NN + n) * 32 + o]       = out0.x + out0.y;
    out[((size_t)(b0 + 8) * NN + n) * 32 + o] = out1.x + out1.y;
}

// f32 fallback path — used only if ws_size is too small for the fp16 repack
__global__ __launch_bounds__(256)
void k_main_f32(const float* __restrict__ X,
                const int* __restrict__ offsets, const int* __restrict__ count,
                const float* __restrict__ dinv,
                const int* __restrict__ csr_src, const float* __restrict__ csr_norm,
                const float* __restrict__ consts,
                float* __restrict__ out) {
    __shared__ float sAgg[NB * 128];
    __shared__ float sMz[256], sMh[256], sCz[32], sCh[32], sWs[16];
    int tid = threadIdx.x;
    int n = blockIdx.x;

    sMz[tid] = consts[tid];
    sMh[tid] = consts[256 + tid];
    if (tid < 32) { sCz[tid] = consts[512 + tid]; sCh[tid] = consts[544 + tid]; }
    if (tid < 16) sWs[tid] = consts[576 + tid];

    int b = tid >> 4, chunk = tid & 15;
    const f32x8* xv = (const f32x8*)X;
    float dn = dinv[n];
    float selfn = dn * dn;
    float acc[8];
    {
        f32x8 w = xv[((size_t)b * NN + n) * 16 + chunk];
        #pragma unroll
        for (int j = 0; j < 8; ++j) acc[j] = selfn * w[j];
    }
    int off = offsets[n], cnt = count[n];
    for (int e = off; e < off + cnt; ++e) {
        int s = csr_src[e];
        float nrm = csr_norm[e];
        f32x8 w = xv[((size_t)b * NN + s) * 16 + chunk];
        #pragma unroll
        for (int j = 0; j < 8; ++j) acc[j] += nrm * w[j];
    }
    #pragma unroll
    for (int j = 0; j < 8; ++j) sAgg[tid * 8 + j] = acc[j];
    __syncthreads();

    int o = tid & 31, b0 = tid >> 5;
    float mz[8], mh[8];
    #pragma unroll
    for (int c = 0; c < 8; ++c) { mz[c] = sMz[c * 32 + o]; mh[c] = sMh[c * 32 + o]; }
    float czo = sCz[o], cho = sCh[o];
    float acc0 = 0.f, acc1 = 0.f;
    #pragma unroll
    for (int t = 0; t < 16; ++t) {
        float uz0 = czo, uh0 = cho, uz1 = czo, uh1 = cho;
        #pragma unroll
        for (int c = 0; c < 8; ++c) {
            float a0 = sAgg[b0 * 128 + c * 16 + t];
            float a1 = sAgg[(b0 + 8) * 128 + c * 16 + t];
            uz0 += a0 * mz[c]; uh0 += a0 * mh[c];
            uz1 += a1 * mz[c]; uh1 += a1 * mh[c];
        }
        float w = sWs[t];
        acc0 += w * gatefn(uz0, uh0);
        acc1 += w * gatefn(uz1, uh1);
    }
    out[((size_t)b0 * NN + n) * 32 + o]       = acc0;
    out[((size_t)(b0 + 8) * NN + n) * 32 + o] = acc1;
}

extern "C" void kernel_launch(void* const* d_in, const int* in_sizes, int n_in,
                              void* d_out, int out_size, void* d_ws, size_t ws_size,
                              hipStream_t stream) {
    const float* X    = (const float*)d_in[0];
    const int*   ei   = (const int*)d_in[1];
    const float* ew   = (const float*)d_in[2];
    const float* attn = (const float*)d_in[3];
    const float* Wcz  = (const float*)d_in[4];
    const float* bcz  = (const float*)d_in[5];
    const float* Wlz  = (const float*)d_in[6];
    const float* blz  = (const float*)d_in[7];
    // d_in[8..11] = Wcr,bcr,Wlr,blr — provably unused (R multiplies H0=0)
    const float* Wch  = (const float*)d_in[12];
    const float* bch  = (const float*)d_in[13];
    const float* Wlh  = (const float*)d_in[14];
    const float* blh  = (const float*)d_in[15];
    float* out = (float*)d_out;

    const size_t x2_bytes = (size_t)NN * 256 * 16;   // 40.96 MB fp16 repack
    const size_t small_bytes = (size_t)NN * 4 * 5 + (size_t)NE * 4 * 2 + 592 * 4;
    bool use_h = (ws_size >= x2_bytes + small_bytes);

    char* p = (char*)d_ws;
    h16x8* X2 = nullptr;
    if (use_h) { X2 = (h16x8*)p; p += x2_bytes; }
    float* deg      = (float*)p; p += NN * 4;
    float* dinv     = (float*)p; p += NN * 4;
    int*   count    = (int*)p;   p += NN * 4;
    int*   offsets  = (int*)p;   p += NN * 4;
    int*   fillptr  = (int*)p;   p += NN * 4;
    int*   csr_src  = (int*)p;   p += NE * 4;
    float* csr_norm = (float*)p; p += NE * 4;
    float* consts   = (float*)p; p += 592 * 4;

    if (use_h) {
        hipLaunchKernelGGL(k_repack, dim3(1280), dim3(256), 0, stream, X, X2);
    }
    hipLaunchKernelGGL(k_zero, dim3((NN + 255) / 256), dim3(256), 0, stream, deg, count);
    hipLaunchKernelGGL(k_degree, dim3((NE + 255) / 256), dim3(256), 0, stream, ei, ew, deg, count);
    hipLaunchKernelGGL(k_scan_consts, dim3(2), dim3(1024), 0, stream,
                       deg, count, dinv, offsets, fillptr,
                       attn, Wcz, bcz, Wlz, blz, Wch, bch, Wlh, blh, consts);
    hipLaunchKernelGGL(k_fill, dim3((NE + 255) / 256), dim3(256), 0, stream,
                       ei, ew, dinv, fillptr, csr_src, csr_norm);
    if (use_h) {
        hipLaunchKernelGGL(k_main_h, dim3(NN), dim3(256), 0, stream,
                           X2, offsets, count, dinv, csr_src, csr_norm, consts, out);
    } else {
        hipLaunchKernelGGL(k_main_f32, dim3(NN), dim3(256), 0, stream,
                           X, offsets, count, dinv, csr_src, csr_norm, consts, out);
    }
}

// Round 6
// 163.159 us; speedup vs baseline: 1.5926x; 1.2318x over previous
//
#include <hip/hip_runtime.h>
#include <stdint.h>

#define NN 10000      // nodes
#define NE 160000     // edges
#define NB 16         // batch
// per (b,n) row: CIN*2P = 8*16 = 128 features, layout [c][t] (t fastest)

typedef __attribute__((ext_vector_type(8))) float f32x8;
typedef __attribute__((ext_vector_type(4))) float f32x4;
typedef __attribute__((ext_vector_type(2))) float f32x2;
typedef __attribute__((ext_vector_type(8))) _Float16 h16x8;

#define AGG_LD 136   // 128 + 8 pad floats per b-row

// edge_index may arrive as int32 (contract) or raw int64 (reference dtype).
// int64 node ids < 2^32 have all-zero high words.
__device__ __forceinline__ int ei_stride(const int* __restrict__ ei) {
    int z = ei[1] | ei[3] | ei[5] | ei[7] | ei[9] | ei[11] | ei[13] | ei[15];
    return (z == 0) ? 2 : 1;
}

__global__ void k_zero(float* deg, int* count) {
    int i = blockIdx.x * blockDim.x + threadIdx.x;
    if (i < NN) { deg[i] = 0.f; count[i] = 0; }
}

// X[b][n][128] f32 -> X2[n][b*128] fp16 (node-major, 4KB/row), grid-stride.
// Also zeroes deg/count (folds k_zero) when dz != nullptr.
__global__ __launch_bounds__(256)
void k_repack(const float* __restrict__ X, h16x8* __restrict__ X2,
              float* dz, int* cz) {
    int gid = blockIdx.x * blockDim.x + threadIdx.x;
    int gsz = gridDim.x * blockDim.x;
    for (int i = gid; i < NN; i += gsz) { dz[i] = 0.f; cz[i] = 0; }
    const int total = NN * 256;
    for (int i = gid; i < total; i += gsz) {
        int n = i >> 8, t = i & 255;
        int b = t >> 4, chunk = t & 15;
        f32x8 w = ((const f32x8*)X)[((size_t)b * NN + n) * 16 + chunk];
        h16x8 h;
        #pragma unroll
        for (int j = 0; j < 8; ++j) h[j] = (_Float16)w[j];
        X2[(size_t)n * 256 + t] = h;
    }
}

__global__ void k_degree(const int* __restrict__ ei, const float* __restrict__ ew,
                         float* deg, int* count) {
    int e = blockIdx.x * blockDim.x + threadIdx.x;
    if (e >= NE) return;
    int stride = ei_stride(ei);
    int d = ei[(size_t)(NE + e) * stride];
    atomicAdd(&deg[d], ew[e]);
    atomicAdd(&count[d], 1);
}

// block 0: exclusive scan of count (wave-shuffle based) -> offsets/fillptr; dinv
// block 1: folded weights Mz,Mh (8x32), cz,ch (32), ws = softmax(attention) (16)
__global__ void k_scan_consts(const float* __restrict__ deg, const int* __restrict__ count,
                              float* dinv, int* offsets, int* fillptr,
                              const float* __restrict__ attn,
                              const float* __restrict__ Wcz, const float* __restrict__ bcz,
                              const float* __restrict__ Wlz, const float* __restrict__ blz,
                              const float* __restrict__ Wch, const float* __restrict__ bch,
                              const float* __restrict__ Wlh, const float* __restrict__ blh,
                              float* consts) {
    int tid = threadIdx.x;
    if (blockIdx.x == 1) {
        if (tid < 256) {
            int c = tid >> 5, o = tid & 31;
            float mz = 0.f, mh = 0.f;
            for (int k = 0; k < 32; ++k) {
                mz += Wcz[c * 32 + k] * Wlz[k * 32 + o];   // Wl rows 0..31 (H0 half is zero)
                mh += Wch[c * 32 + k] * Wlh[k * 32 + o];
            }
            consts[tid] = mz;
            consts[256 + tid] = mh;
        }
        if (tid < 32) {
            float cz = blz[tid], ch = blh[tid];
            for (int k = 0; k < 32; ++k) {
                cz += bcz[k] * Wlz[k * 32 + tid];
                ch += bch[k] * Wlh[k * 32 + tid];
            }
            consts[512 + tid] = cz;
            consts[544 + tid] = ch;
        }
        if (tid == 0) {
            float a[16], m = -1e30f, s = 0.f;
            for (int t = 0; t < 16; ++t) { a[t] = attn[t]; m = fmaxf(m, a[t]); }
            for (int t = 0; t < 16; ++t) { a[t] = __expf(a[t] - m); s += a[t]; }
            for (int t = 0; t < 16; ++t) consts[576 + t] = a[t] / s;
        }
        return;
    }
    // ---- block 0: scan over NN counts, 1024 threads = 16 waves ----
    int lane = tid & 63, wv = tid >> 6;
    __shared__ int wsum[16];
    __shared__ int carry;
    if (tid == 0) carry = 0;
    __syncthreads();
    for (int base = 0; base < NN; base += 1024) {
        int i = base + tid;
        int v = (i < NN) ? count[i] : 0;
        int x = v;
        #pragma unroll
        for (int s = 1; s < 64; s <<= 1) {
            int y = __shfl_up(x, s, 64);
            if (lane >= s) x += y;
        }
        if (lane == 63) wsum[wv] = x;
        __syncthreads();
        if (wv == 0 && lane < 16) {
            int y = wsum[lane];
            #pragma unroll
            for (int s = 1; s < 16; s <<= 1) {
                int z = __shfl_up(y, s, 64);
                if (lane >= s) y += z;
            }
            wsum[lane] = y;
        }
        __syncthreads();
        int wbase = (wv == 0) ? 0 : wsum[wv - 1];
        int incl = carry + wbase + x;
        int excl = incl - v;
        if (i < NN) { offsets[i] = excl; fillptr[i] = excl; }
        __syncthreads();
        if (tid == 1023) carry = incl;
        __syncthreads();
    }
    for (int i = tid; i < NN; i += 1024) dinv[i] = rsqrtf(deg[i] + 1.0f);
}

__global__ void k_fill(const int* __restrict__ ei, const float* __restrict__ ew,
                       const float* __restrict__ dinv,
                       int* fillptr, int* csr_src, float* csr_norm) {
    int e = blockIdx.x * blockDim.x + threadIdx.x;
    if (e >= NE) return;
    int stride = ei_stride(ei);
    int s = ei[(size_t)e * stride];
    int d = ei[(size_t)(NE + e) * stride];
    int pos = atomicAdd(&fillptr[d], 1);
    csr_src[pos] = s;
    csr_norm[pos] = dinv[s] * ew[e] * dinv[d];
}

// (1-sigmoid(uz)) * tanh(uh) = (e^{2uh}-1) / ((1+e^{uz})(e^{2uh}+1))
// 2 transcendental exp + 1 rcp (vs 2 exp + 2 rcp before).
__device__ __forceinline__ float gatefn(float uz, float uh) {
    float ez = __expf(uz);
    float eh = __expf(2.f * uh);
    return (eh - 1.f) * __builtin_amdgcn_rcpf((1.f + ez) * (eh + 1.f));
}

// fp16 node-major gather + fused transform.
// sAgg layout: [b][tp][c][half] float, row stride AGG_LD. tp=t>>1, half=t&1.
__global__ __launch_bounds__(256)
void k_main_h(const h16x8* __restrict__ X2,
              const int* __restrict__ offsets, const int* __restrict__ count,
              const float* __restrict__ dinv,
              const int* __restrict__ csr_src, const float* __restrict__ csr_norm,
              const float* __restrict__ consts,
              float* __restrict__ out) {
    __shared__ float sAgg[NB * AGG_LD];
    __shared__ float sMz[256], sMh[256], sCz[32], sCh[32], sWs[16];
    int tid = threadIdx.x;
    int n = blockIdx.x;

    sMz[tid] = consts[tid];
    sMh[tid] = consts[256 + tid];
    if (tid < 32) { sCz[tid] = consts[512 + tid]; sCh[tid] = consts[544 + tid]; }
    if (tid < 16) sWs[tid] = consts[576 + tid];

    // ---- Phase A: gather, software-pipelined (8 loads in flight) ----
    int b = tid >> 4;
    int chunk = tid & 15;
    float dn = dinv[n];
    float selfn = dn * dn;
    float acc[8];
    {
        h16x8 w = X2[(size_t)n * 256 + tid];
        #pragma unroll
        for (int j = 0; j < 8; ++j) acc[j] = selfn * (float)w[j];
    }
    int off = offsets[n], cnt = count[n];
    const int*   sp  = csr_src + off;
    const float* npv = csr_norm + off;
    int e = 0;
    if (cnt >= 8) {
        int s0 = sp[0], s1 = sp[1], s2 = sp[2], s3 = sp[3];
        h16x8 a0 = X2[(size_t)s0 * 256 + tid];
        h16x8 a1 = X2[(size_t)s1 * 256 + tid];
        h16x8 a2 = X2[(size_t)s2 * 256 + tid];
        h16x8 a3 = X2[(size_t)s3 * 256 + tid];
        for (e = 4; e + 4 <= cnt; e += 4) {
            int t0 = sp[e], t1 = sp[e + 1], t2 = sp[e + 2], t3 = sp[e + 3];
            h16x8 b0 = X2[(size_t)t0 * 256 + tid];
            h16x8 b1 = X2[(size_t)t1 * 256 + tid];
            h16x8 b2 = X2[(size_t)t2 * 256 + tid];
            h16x8 b3 = X2[(size_t)t3 * 256 + tid];
            __builtin_amdgcn_sched_barrier(0);   // keep b-loads issued before a-consume
            float n0 = npv[e - 4], n1 = npv[e - 3], n2 = npv[e - 2], n3 = npv[e - 1];
            #pragma unroll
            for (int j = 0; j < 8; ++j) acc[j] += n0 * (float)a0[j];
            #pragma unroll
            for (int j = 0; j < 8; ++j) acc[j] += n1 * (float)a1[j];
            #pragma unroll
            for (int j = 0; j < 8; ++j) acc[j] += n2 * (float)a2[j];
            #pragma unroll
            for (int j = 0; j < 8; ++j) acc[j] += n3 * (float)a3[j];
            a0 = b0; a1 = b1; a2 = b2; a3 = b3;
        }
        float n0 = npv[e - 4], n1 = npv[e - 3], n2 = npv[e - 2], n3 = npv[e - 1];
        #pragma unroll
        for (int j = 0; j < 8; ++j) acc[j] += n0 * (float)a0[j];
        #pragma unroll
        for (int j = 0; j < 8; ++j) acc[j] += n1 * (float)a1[j];
        #pragma unroll
        for (int j = 0; j < 8; ++j) acc[j] += n2 * (float)a2[j];
        #pragma unroll
        for (int j = 0; j < 8; ++j) acc[j] += n3 * (float)a3[j];
    }
    for (; e < cnt; ++e) {
        int s = sp[e];
        float nrm = npv[e];
        h16x8 w = X2[(size_t)s * 256 + tid];
        #pragma unroll
        for (int j = 0; j < 8; ++j) acc[j] += nrm * (float)w[j];
    }
    // store: acc[j] = A[b][c][t=tbase+j] -> sAgg[b*AGG_LD + tp*16 + c*2 + (t&1)]
    {
        int c = chunk >> 1;
        int tpb = (chunk & 1) * 4;
        float* rowp = &sAgg[b * AGG_LD + c * 2];
        #pragma unroll
        for (int k = 0; k < 4; ++k) {
            f32x2 v = {acc[2 * k], acc[2 * k + 1]};
            *(f32x2*)&rowp[(tpb + k) * 16] = v;
        }
    }
    __syncthreads();

    // ---- Phase B ----
    int o = tid & 31, b0 = tid >> 5;
    float mz[8], mh[8];
    #pragma unroll
    for (int c = 0; c < 8; ++c) { mz[c] = sMz[c * 32 + o]; mh[c] = sMh[c * 32 + o]; }
    float czo = sCz[o], cho = sCh[o];
    const f32x4* r0 = (const f32x4*)&sAgg[b0 * AGG_LD];
    const f32x4* r1 = (const f32x4*)&sAgg[(b0 + 8) * AGG_LD];
    f32x2 out0 = {0.f, 0.f}, out1 = {0.f, 0.f};
    #pragma unroll
    for (int tp = 0; tp < 8; ++tp) {
        f32x4 A0[4], A1[4];
        #pragma unroll
        for (int k = 0; k < 4; ++k) { A0[k] = r0[tp * 4 + k]; A1[k] = r1[tp * 4 + k]; }
        f32x2 uz0 = {czo, czo}, uh0 = {cho, cho};
        f32x2 uz1 = {czo, czo}, uh1 = {cho, cho};
        #pragma unroll
        for (int k = 0; k < 4; ++k) {
            f32x2 p0 = A0[k].xy, q0 = A0[k].zw;
            f32x2 p1 = A1[k].xy, q1 = A1[k].zw;
            float m0 = mz[2 * k], m1 = mz[2 * k + 1];
            float v0 = mh[2 * k], v1 = mh[2 * k + 1];
            uz0 += p0 * m0; uz0 += q0 * m1;
            uh0 += p0 * v0; uh0 += q0 * v1;
            uz1 += p1 * m0; uz1 += q1 * m1;
            uh1 += p1 * v0; uh1 += q1 * v1;
        }
        f32x2 wsp = {sWs[2 * tp], sWs[2 * tp + 1]};
        f32x2 g0, g1;
        g0.x = gatefn(uz0.x, uh0.x); g0.y = gatefn(uz0.y, uh0.y);
        g1.x = gatefn(uz1.x, uh1.x); g1.y = gatefn(uz1.y, uh1.y);
        out0 += wsp * g0;
        out1 += wsp * g1;
    }
    out[((size_t)b0 * NN + n) * 32 + o]       = out0.x + out0.y;
    out[((size_t)(b0 + 8) * NN + n) * 32 + o] = out1.x + out1.y;
}

// f32 fallback path — used only if ws_size is too small for the fp16 repack
__global__ __launch_bounds__(256)
void k_main_f32(const float* __restrict__ X,
                const int* __restrict__ offsets, const int* __restrict__ count,
                const float* __restrict__ dinv,
                const int* __restrict__ csr_src, const float* __restrict__ csr_norm,
                const float* __restrict__ consts,
                float* __restrict__ out) {
    __shared__ float sAgg[NB * 128];
    __shared__ float sMz[256], sMh[256], sCz[32], sCh[32], sWs[16];
    int tid = threadIdx.x;
    int n = blockIdx.x;

    sMz[tid] = consts[tid];
    sMh[tid] = consts[256 + tid];
    if (tid < 32) { sCz[tid] = consts[512 + tid]; sCh[tid] = consts[544 + tid]; }
    if (tid < 16) sWs[tid] = consts[576 + tid];

    int b = tid >> 4, chunk = tid & 15;
    const f32x8* xv = (const f32x8*)X;
    float dn = dinv[n];
    float selfn = dn * dn;
    float acc[8];
    {
        f32x8 w = xv[((size_t)b * NN + n) * 16 + chunk];
        #pragma unroll
        for (int j = 0; j < 8; ++j) acc[j] = selfn * w[j];
    }
    int off = offsets[n], cnt = count[n];
    for (int e = off; e < off + cnt; ++e) {
        int s = csr_src[e];
        float nrm = csr_norm[e];
        f32x8 w = xv[((size_t)b * NN + s) * 16 + chunk];
        #pragma unroll
        for (int j = 0; j < 8; ++j) acc[j] += nrm * w[j];
    }
    #pragma unroll
    for (int j = 0; j < 8; ++j) sAgg[tid * 8 + j] = acc[j];
    __syncthreads();

    int o = tid & 31, b0 = tid >> 5;
    float mz[8], mh[8];
    #pragma unroll
    for (int c = 0; c < 8; ++c) { mz[c] = sMz[c * 32 + o]; mh[c] = sMh[c * 32 + o]; }
    float czo = sCz[o], cho = sCh[o];
    float acc0 = 0.f, acc1 = 0.f;
    #pragma unroll
    for (int t = 0; t < 16; ++t) {
        float uz0 = czo, uh0 = cho, uz1 = czo, uh1 = cho;
        #pragma unroll
        for (int c = 0; c < 8; ++c) {
            float a0 = sAgg[b0 * 128 + c * 16 + t];
            float a1 = sAgg[(b0 + 8) * 128 + c * 16 + t];
            uz0 += a0 * mz[c]; uh0 += a0 * mh[c];
            uz1 += a1 * mz[c]; uh1 += a1 * mh[c];
        }
        float w = sWs[t];
        acc0 += w * gatefn(uz0, uh0);
        acc1 += w * gatefn(uz1, uh1);
    }
    out[((size_t)b0 * NN + n) * 32 + o]       = acc0;
    out[((size_t)(b0 + 8) * NN + n) * 32 + o] = acc1;
}

extern "C" void kernel_launch(void* const* d_in, const int* in_sizes, int n_in,
                              void* d_out, int out_size, void* d_ws, size_t ws_size,
                              hipStream_t stream) {
    const float* X    = (const float*)d_in[0];
    const int*   ei   = (const int*)d_in[1];
    const float* ew   = (const float*)d_in[2];
    const float* attn = (const float*)d_in[3];
    const float* Wcz  = (const float*)d_in[4];
    const float* bcz  = (const float*)d_in[5];
    const float* Wlz  = (const float*)d_in[6];
    const float* blz  = (const float*)d_in[7];
    // d_in[8..11] = Wcr,bcr,Wlr,blr — provably unused (R multiplies H0=0)
    const float* Wch  = (const float*)d_in[12];
    const float* bch  = (const float*)d_in[13];
    const float* Wlh  = (const float*)d_in[14];
    const float* blh  = (const float*)d_in[15];
    float* out = (float*)d_out;

    const size_t x2_bytes = (size_t)NN * 256 * 16;   // 40.96 MB fp16 repack
    const size_t small_bytes = (size_t)NN * 4 * 5 + (size_t)NE * 4 * 2 + 592 * 4;
    bool use_h = (ws_size >= x2_bytes + small_bytes);

    char* p = (char*)d_ws;
    h16x8* X2 = nullptr;
    if (use_h) { X2 = (h16x8*)p; p += x2_bytes; }
    float* deg      = (float*)p; p += NN * 4;
    float* dinv     = (float*)p; p += NN * 4;
    int*   count    = (int*)p;   p += NN * 4;
    int*   offsets  = (int*)p;   p += NN * 4;
    int*   fillptr  = (int*)p;   p += NN * 4;
    int*   csr_src  = (int*)p;   p += NE * 4;
    float* csr_norm = (float*)p; p += NE * 4;
    float* consts   = (float*)p; p += 592 * 4;

    if (use_h) {
        hipLaunchKernelGGL(k_repack, dim3(1280), dim3(256), 0, stream, X, X2, deg, count);
    } else {
        hipLaunchKernelGGL(k_zero, dim3((NN + 255) / 256), dim3(256), 0, stream, deg, count);
    }
    hipLaunchKernelGGL(k_degree, dim3((NE + 255) / 256), dim3(256), 0, stream, ei, ew, deg, count);
    hipLaunchKernelGGL(k_scan_consts, dim3(2), dim3(1024), 0, stream,
                       deg, count, dinv, offsets, fillptr,
                       attn, Wcz, bcz, Wlz, blz, Wch, bch, Wlh, blh, consts);
    hipLaunchKernelGGL(k_fill, dim3((NE + 255) / 256), dim3(256), 0, stream,
                       ei, ew, dinv, fillptr, csr_src, csr_norm);
    if (use_h) {
        hipLaunchKernelGGL(k_main_h, dim3(NN), dim3(256), 0, stream,
                           X2, offsets, count, dinv, csr_src, csr_norm, consts, out);
    } else {
        hipLaunchKernelGGL(k_main_f32, dim3(NN), dim3(256), 0, stream,
                           X, offsets, count, dinv, csr_src, csr_norm, consts, out);
    }
}

// Round 7
// 155.575 us; speedup vs baseline: 1.6702x; 1.0488x over previous
//
#include <hip/hip_runtime.h>
#include <stdint.h>

#define NN 10000      // nodes
#define NE 160000     // edges
#define NB 16         // batch
#define NT 8          // nodes per block in k_main_h (tile)
// per (b,n) row: CIN*2P = 8*16 = 128 features, layout [c][t] (t fastest)

typedef __attribute__((ext_vector_type(8))) float f32x8;
typedef __attribute__((ext_vector_type(4))) float f32x4;
typedef __attribute__((ext_vector_type(2))) float f32x2;
typedef __attribute__((ext_vector_type(8))) _Float16 h16x8;

#define AGG_LD 136   // 128 + 8 pad floats per row

// edge_index may arrive as int32 (contract) or raw int64 (reference dtype).
// int64 node ids < 2^32 have all-zero high words.
__device__ __forceinline__ int ei_stride(const int* __restrict__ ei) {
    int z = ei[1] | ei[3] | ei[5] | ei[7] | ei[9] | ei[11] | ei[13] | ei[15];
    return (z == 0) ? 2 : 1;
}

__global__ void k_zero(float* deg, int* count) {
    int i = blockIdx.x * blockDim.x + threadIdx.x;
    if (i < NN) { deg[i] = 0.f; count[i] = 0; }
}

// X[b][n][128] f32 -> X2[bp][n][half][128] fp16 (bp = b>>1, half = b&1).
// Per (bp,n): 512 contiguous bytes = the 2-batch slice one gather block reads.
// Also zeroes deg/count (folds k_zero).
__global__ __launch_bounds__(256)
void k_repack(const float* __restrict__ X, h16x8* __restrict__ X2,
              float* dz, int* cz) {
    int gid = blockIdx.x * blockDim.x + threadIdx.x;
    int gsz = gridDim.x * blockDim.x;
    for (int i = gid; i < NN; i += gsz) { dz[i] = 0.f; cz[i] = 0; }
    const int total = NN * 256;
    for (int i = gid; i < total; i += gsz) {
        int n = i >> 8, t = i & 255;
        int b = t >> 4, chunk = t & 15;
        f32x8 w = ((const f32x8*)X)[((size_t)b * NN + n) * 16 + chunk];
        h16x8 h;
        #pragma unroll
        for (int j = 0; j < 8; ++j) h[j] = (_Float16)w[j];
        X2[((size_t)(b >> 1) * NN + n) * 32 + (b & 1) * 16 + chunk] = h;
    }
}

__global__ void k_degree(const int* __restrict__ ei, const float* __restrict__ ew,
                         float* deg, int* count) {
    int e = blockIdx.x * blockDim.x + threadIdx.x;
    if (e >= NE) return;
    int stride = ei_stride(ei);
    int d = ei[(size_t)(NE + e) * stride];
    atomicAdd(&deg[d], ew[e]);
    atomicAdd(&count[d], 1);
}

// block 0: exclusive scan of count (wave-shuffle based) -> offsets/fillptr; dinv
// block 1: folded weights Mz,Mh (8x32), cz,ch (32), ws = softmax(attention) (16)
__global__ void k_scan_consts(const float* __restrict__ deg, const int* __restrict__ count,
                              float* dinv, int* offsets, int* fillptr,
                              const float* __restrict__ attn,
                              const float* __restrict__ Wcz, const float* __restrict__ bcz,
                              const float* __restrict__ Wlz, const float* __restrict__ blz,
                              const float* __restrict__ Wch, const float* __restrict__ bch,
                              const float* __restrict__ Wlh, const float* __restrict__ blh,
                              float* consts) {
    int tid = threadIdx.x;
    if (blockIdx.x == 1) {
        if (tid < 256) {
            int c = tid >> 5, o = tid & 31;
            float mz = 0.f, mh = 0.f;
            for (int k = 0; k < 32; ++k) {
                mz += Wcz[c * 32 + k] * Wlz[k * 32 + o];   // Wl rows 0..31 (H0 half is zero)
                mh += Wch[c * 32 + k] * Wlh[k * 32 + o];
            }
            consts[tid] = mz;
            consts[256 + tid] = mh;
        }
        if (tid < 32) {
            float cz = blz[tid], ch = blh[tid];
            for (int k = 0; k < 32; ++k) {
                cz += bcz[k] * Wlz[k * 32 + tid];
                ch += bch[k] * Wlh[k * 32 + tid];
            }
            consts[512 + tid] = cz;
            consts[544 + tid] = ch;
        }
        if (tid == 0) {
            float a[16], m = -1e30f, s = 0.f;
            for (int t = 0; t < 16; ++t) { a[t] = attn[t]; m = fmaxf(m, a[t]); }
            for (int t = 0; t < 16; ++t) { a[t] = __expf(a[t] - m); s += a[t]; }
            for (int t = 0; t < 16; ++t) consts[576 + t] = a[t] / s;
        }
        return;
    }
    // ---- block 0: scan over NN counts, 1024 threads = 16 waves ----
    int lane = tid & 63, wv = tid >> 6;
    __shared__ int wsum[16];
    __shared__ int carry;
    if (tid == 0) carry = 0;
    __syncthreads();
    for (int base = 0; base < NN; base += 1024) {
        int i = base + tid;
        int v = (i < NN) ? count[i] : 0;
        int x = v;
        #pragma unroll
        for (int s = 1; s < 64; s <<= 1) {
            int y = __shfl_up(x, s, 64);
            if (lane >= s) x += y;
        }
        if (lane == 63) wsum[wv] = x;
        __syncthreads();
        if (wv == 0 && lane < 16) {
            int y = wsum[lane];
            #pragma unroll
            for (int s = 1; s < 16; s <<= 1) {
                int z = __shfl_up(y, s, 64);
                if (lane >= s) y += z;
            }
            wsum[lane] = y;
        }
        __syncthreads();
        int wbase = (wv == 0) ? 0 : wsum[wv - 1];
        int incl = carry + wbase + x;
        int excl = incl - v;
        if (i < NN) { offsets[i] = excl; fillptr[i] = excl; }
        __syncthreads();
        if (tid == 1023) carry = incl;
        __syncthreads();
    }
    for (int i = tid; i < NN; i += 1024) dinv[i] = rsqrtf(deg[i] + 1.0f);
}

__global__ void k_fill(const int* __restrict__ ei, const float* __restrict__ ew,
                       const float* __restrict__ dinv,
                       int* fillptr, int* csr_src, float* csr_norm) {
    int e = blockIdx.x * blockDim.x + threadIdx.x;
    if (e >= NE) return;
    int stride = ei_stride(ei);
    int s = ei[(size_t)e * stride];
    int d = ei[(size_t)(NE + e) * stride];
    int pos = atomicAdd(&fillptr[d], 1);
    csr_src[pos] = s;
    csr_norm[pos] = dinv[s] * ew[e] * dinv[d];
}

// (1-sigmoid(uz)) * tanh(uh) = (e^{2uh}-1) / ((1+e^{uz})(e^{2uh}+1))
__device__ __forceinline__ float gatefn(float uz, float uh) {
    float ez = __expf(uz);
    float eh = __expf(2.f * uh);
    return (eh - 1.f) * __builtin_amdgcn_rcpf((1.f + ez) * (eh + 1.f));
}

// Batch-partitioned gather: block = (bp, tile of NT nodes); handles batches
// {2bp, 2bp+1} only. bp = blockIdx&7 so (assuming round-robin workgroup->XCD
// dispatch) each XCD's gather working set is NN*512B = 5.1MB ~ its private L2.
// Thread: ns = tid>>5 (node in tile), lane = tid&31 (16B feature chunk of the
// 512B 2-batch slice).
__global__ __launch_bounds__(256)
void k_main_h(const h16x8* __restrict__ X2,
              const int* __restrict__ offsets, const int* __restrict__ count,
              const float* __restrict__ dinv,
              const int* __restrict__ csr_src, const float* __restrict__ csr_norm,
              const float* __restrict__ consts,
              float* __restrict__ out) {
    __shared__ float sAgg[2 * NT * AGG_LD];   // row = ns*2 + half
    __shared__ float sMz[256], sMh[256], sCz[32], sCh[32], sWs[16];
    int tid = threadIdx.x;
    int bp   = blockIdx.x & 7;
    int tile = blockIdx.x >> 3;

    sMz[tid] = consts[tid];
    sMh[tid] = consts[256 + tid];
    if (tid < 32) { sCz[tid] = consts[512 + tid]; sCh[tid] = consts[544 + tid]; }
    if (tid < 16) sWs[tid] = consts[576 + tid];

    // ---- Phase A: gather, software-pipelined ----
    int ns = tid >> 5;
    int lane = tid & 31;
    int n = tile * NT + ns;
    const h16x8* xb = X2 + ((size_t)bp * NN) * 32;   // this bp's 5.1MB slab
    float dn = dinv[n];
    float selfn = dn * dn;
    float acc[8];
    {
        h16x8 w = xb[(size_t)n * 32 + lane];
        #pragma unroll
        for (int j = 0; j < 8; ++j) acc[j] = selfn * (float)w[j];
    }
    int off = offsets[n], cnt = count[n];
    const int*   sp  = csr_src + off;
    const float* npv = csr_norm + off;
    int e = 0;
    if (cnt >= 8) {
        int s0 = sp[0], s1 = sp[1], s2 = sp[2], s3 = sp[3];
        h16x8 a0 = xb[(size_t)s0 * 32 + lane];
        h16x8 a1 = xb[(size_t)s1 * 32 + lane];
        h16x8 a2 = xb[(size_t)s2 * 32 + lane];
        h16x8 a3 = xb[(size_t)s3 * 32 + lane];
        for (e = 4; e + 4 <= cnt; e += 4) {
            int t0 = sp[e], t1 = sp[e + 1], t2 = sp[e + 2], t3 = sp[e + 3];
            h16x8 b0 = xb[(size_t)t0 * 32 + lane];
            h16x8 b1 = xb[(size_t)t1 * 32 + lane];
            h16x8 b2 = xb[(size_t)t2 * 32 + lane];
            h16x8 b3 = xb[(size_t)t3 * 32 + lane];
            __builtin_amdgcn_sched_barrier(0);   // keep b-loads issued before a-consume
            float n0 = npv[e - 4], n1 = npv[e - 3], n2 = npv[e - 2], n3 = npv[e - 1];
            #pragma unroll
            for (int j = 0; j < 8; ++j) acc[j] += n0 * (float)a0[j];
            #pragma unroll
            for (int j = 0; j < 8; ++j) acc[j] += n1 * (float)a1[j];
            #pragma unroll
            for (int j = 0; j < 8; ++j) acc[j] += n2 * (float)a2[j];
            #pragma unroll
            for (int j = 0; j < 8; ++j) acc[j] += n3 * (float)a3[j];
            a0 = b0; a1 = b1; a2 = b2; a3 = b3;
        }
        float n0 = npv[e - 4], n1 = npv[e - 3], n2 = npv[e - 2], n3 = npv[e - 1];
        #pragma unroll
        for (int j = 0; j < 8; ++j) acc[j] += n0 * (float)a0[j];
        #pragma unroll
        for (int j = 0; j < 8; ++j) acc[j] += n1 * (float)a1[j];
        #pragma unroll
        for (int j = 0; j < 8; ++j) acc[j] += n2 * (float)a2[j];
        #pragma unroll
        for (int j = 0; j < 8; ++j) acc[j] += n3 * (float)a3[j];
    }
    for (; e < cnt; ++e) {
        int s = sp[e];
        float nrm = npv[e];
        h16x8 w = xb[(size_t)s * 32 + lane];
        #pragma unroll
        for (int j = 0; j < 8; ++j) acc[j] += nrm * (float)w[j];
    }
    // store: row r = ns*2 + half; within row the round-5 [tp][c][half2] layout
    {
        int half = lane >> 4;
        int chunk = lane & 15;
        int r = ns * 2 + half;
        int c = chunk >> 1;
        int tpb = (chunk & 1) * 4;
        float* rowp = &sAgg[r * AGG_LD + c * 2];
        #pragma unroll
        for (int k = 0; k < 4; ++k) {
            f32x2 v = {acc[2 * k], acc[2 * k + 1]};
            *(f32x2*)&rowp[(tpb + k) * 16] = v;
        }
    }
    __syncthreads();

    // ---- Phase B: thread handles (ns2, o) for b_local = 0,1 ----
    int o = tid & 31, ns2 = tid >> 5;
    int n2 = tile * NT + ns2;
    float mz[8], mh[8];
    #pragma unroll
    for (int c = 0; c < 8; ++c) { mz[c] = sMz[c * 32 + o]; mh[c] = sMh[c * 32 + o]; }
    float czo = sCz[o], cho = sCh[o];
    const f32x4* r0 = (const f32x4*)&sAgg[(ns2 * 2 + 0) * AGG_LD];
    const f32x4* r1 = (const f32x4*)&sAgg[(ns2 * 2 + 1) * AGG_LD];
    f32x2 out0 = {0.f, 0.f}, out1 = {0.f, 0.f};
    #pragma unroll
    for (int tp = 0; tp < 8; ++tp) {
        f32x4 A0[4], A1[4];
        #pragma unroll
        for (int k = 0; k < 4; ++k) { A0[k] = r0[tp * 4 + k]; A1[k] = r1[tp * 4 + k]; }
        f32x2 uz0 = {czo, czo}, uh0 = {cho, cho};
        f32x2 uz1 = {czo, czo}, uh1 = {cho, cho};
        #pragma unroll
        for (int k = 0; k < 4; ++k) {
            f32x2 p0 = A0[k].xy, q0 = A0[k].zw;
            f32x2 p1 = A1[k].xy, q1 = A1[k].zw;
            float m0 = mz[2 * k], m1 = mz[2 * k + 1];
            float v0 = mh[2 * k], v1 = mh[2 * k + 1];
            uz0 += p0 * m0; uz0 += q0 * m1;
            uh0 += p0 * v0; uh0 += q0 * v1;
            uz1 += p1 * m0; uz1 += q1 * m1;
            uh1 += p1 * v0; uh1 += q1 * v1;
        }
        f32x2 wsp = {sWs[2 * tp], sWs[2 * tp + 1]};
        f32x2 g0, g1;
        g0.x = gatefn(uz0.x, uh0.x); g0.y = gatefn(uz0.y, uh0.y);
        g1.x = gatefn(uz1.x, uh1.x); g1.y = gatefn(uz1.y, uh1.y);
        out0 += wsp * g0;
        out1 += wsp * g1;
    }
    out[((size_t)(bp * 2 + 0) * NN + n2) * 32 + o] = out0.x + out0.y;
    out[((size_t)(bp * 2 + 1) * NN + n2) * 32 + o] = out1.x + out1.y;
}

// f32 fallback path — used only if ws_size is too small for the fp16 repack
__global__ __launch_bounds__(256)
void k_main_f32(const float* __restrict__ X,
                const int* __restrict__ offsets, const int* __restrict__ count,
                const float* __restrict__ dinv,
                const int* __restrict__ csr_src, const float* __restrict__ csr_norm,
                const float* __restrict__ consts,
                float* __restrict__ out) {
    __shared__ float sAgg[NB * 128];
    __shared__ float sMz[256], sMh[256], sCz[32], sCh[32], sWs[16];
    int tid = threadIdx.x;
    int n = blockIdx.x;

    sMz[tid] = consts[tid];
    sMh[tid] = consts[256 + tid];
    if (tid < 32) { sCz[tid] = consts[512 + tid]; sCh[tid] = consts[544 + tid]; }
    if (tid < 16) sWs[tid] = consts[576 + tid];

    int b = tid >> 4, chunk = tid & 15;
    const f32x8* xv = (const f32x8*)X;
    float dn = dinv[n];
    float selfn = dn * dn;
    float acc[8];
    {
        f32x8 w = xv[((size_t)b * NN + n) * 16 + chunk];
        #pragma unroll
        for (int j = 0; j < 8; ++j) acc[j] = selfn * w[j];
    }
    int off = offsets[n], cnt = count[n];
    for (int e = off; e < off + cnt; ++e) {
        int s = csr_src[e];
        float nrm = csr_norm[e];
        f32x8 w = xv[((size_t)b * NN + s) * 16 + chunk];
        #pragma unroll
        for (int j = 0; j < 8; ++j) acc[j] += nrm * w[j];
    }
    #pragma unroll
    for (int j = 0; j < 8; ++j) sAgg[tid * 8 + j] = acc[j];
    __syncthreads();

    int o = tid & 31, b0 = tid >> 5;
    float mz[8], mh[8];
    #pragma unroll
    for (int c = 0; c < 8; ++c) { mz[c] = sMz[c * 32 + o]; mh[c] = sMh[c * 32 + o]; }
    float czo = sCz[o], cho = sCh[o];
    float acc0 = 0.f, acc1 = 0.f;
    #pragma unroll
    for (int t = 0; t < 16; ++t) {
        float uz0 = czo, uh0 = cho, uz1 = czo, uh1 = cho;
        #pragma unroll
        for (int c = 0; c < 8; ++c) {
            float a0 = sAgg[b0 * 128 + c * 16 + t];
            float a1 = sAgg[(b0 + 8) * 128 + c * 16 + t];
            uz0 += a0 * mz[c]; uh0 += a0 * mh[c];
            uz1 += a1 * mz[c]; uh1 += a1 * mh[c];
        }
        float w = sWs[t];
        acc0 += w * gatefn(uz0, uh0);
        acc1 += w * gatefn(uz1, uh1);
    }
    out[((size_t)b0 * NN + n) * 32 + o]       = acc0;
    out[((size_t)(b0 + 8) * NN + n) * 32 + o] = acc1;
}

extern "C" void kernel_launch(void* const* d_in, const int* in_sizes, int n_in,
                              void* d_out, int out_size, void* d_ws, size_t ws_size,
                              hipStream_t stream) {
    const float* X    = (const float*)d_in[0];
    const int*   ei   = (const int*)d_in[1];
    const float* ew   = (const float*)d_in[2];
    const float* attn = (const float*)d_in[3];
    const float* Wcz  = (const float*)d_in[4];
    const float* bcz  = (const float*)d_in[5];
    const float* Wlz  = (const float*)d_in[6];
    const float* blz  = (const float*)d_in[7];
    // d_in[8..11] = Wcr,bcr,Wlr,blr — provably unused (R multiplies H0=0)
    const float* Wch  = (const float*)d_in[12];
    const float* bch  = (const float*)d_in[13];
    const float* Wlh  = (const float*)d_in[14];
    const float* blh  = (const float*)d_in[15];
    float* out = (float*)d_out;

    const size_t x2_bytes = (size_t)NN * 256 * 16;   // 40.96 MB fp16 repack
    const size_t small_bytes = (size_t)NN * 4 * 5 + (size_t)NE * 4 * 2 + 592 * 4;
    bool use_h = (ws_size >= x2_bytes + small_bytes);

    char* p = (char*)d_ws;
    h16x8* X2 = nullptr;
    if (use_h) { X2 = (h16x8*)p; p += x2_bytes; }
    float* deg      = (float*)p; p += NN * 4;
    float* dinv     = (float*)p; p += NN * 4;
    int*   count    = (int*)p;   p += NN * 4;
    int*   offsets  = (int*)p;   p += NN * 4;
    int*   fillptr  = (int*)p;   p += NN * 4;
    int*   csr_src  = (int*)p;   p += NE * 4;
    float* csr_norm = (float*)p; p += NE * 4;
    float* consts   = (float*)p; p += 592 * 4;

    if (use_h) {
        hipLaunchKernelGGL(k_repack, dim3(1280), dim3(256), 0, stream, X, X2, deg, count);
    } else {
        hipLaunchKernelGGL(k_zero, dim3((NN + 255) / 256), dim3(256), 0, stream, deg, count);
    }
    hipLaunchKernelGGL(k_degree, dim3((NE + 255) / 256), dim3(256), 0, stream, ei, ew, deg, count);
    hipLaunchKernelGGL(k_scan_consts, dim3(2), dim3(1024), 0, stream,
                       deg, count, dinv, offsets, fillptr,
                       attn, Wcz, bcz, Wlz, blz, Wch, bch, Wlh, blh, consts);
    hipLaunchKernelGGL(k_fill, dim3((NE + 255) / 256), dim3(256), 0, stream,
                       ei, ew, dinv, fillptr, csr_src, csr_norm);
    if (use_h) {
        hipLaunchKernelGGL(k_main_h, dim3((NN / NT) * 8), dim3(256), 0, stream,
                           X2, offsets, count, dinv, csr_src, csr_norm, consts, out);
    } else {
        hipLaunchKernelGGL(k_main_f32, dim3(NN), dim3(256), 0, stream,
                           X, offsets, count, dinv, csr_src, csr_norm, consts, out);
    }
}

// Round 8
// 154.029 us; speedup vs baseline: 1.6870x; 1.0100x over previous
//
#include <hip/hip_runtime.h>
#include <stdint.h>

#define NN 10000      // nodes
#define NE 160000     // edges
#define NB 16         // batch
#define NT 4          // nodes per block in k_main_h (1 wave = 1 node)
// per (b,n) row: CIN*2P = 8*16 = 128 features, layout [c][t] (t fastest)

typedef __attribute__((ext_vector_type(8))) float f32x8;
typedef __attribute__((ext_vector_type(4))) float f32x4;
typedef __attribute__((ext_vector_type(2))) float f32x2;
typedef __attribute__((ext_vector_type(8))) _Float16 h16x8;

#define AGG_LD 136   // 128 + 8 pad floats per row

// edge_index may arrive as int32 (contract) or raw int64 (reference dtype).
// int64 node ids < 2^32 have all-zero high words.
__device__ __forceinline__ int ei_stride(const int* __restrict__ ei) {
    int z = ei[1] | ei[3] | ei[5] | ei[7] | ei[9] | ei[11] | ei[13] | ei[15];
    return (z == 0) ? 2 : 1;
}

// Fused prep: degree atomics + (optional) fp16 repack + folded consts.
// deg/count must be zeroed before this kernel (hipMemsetAsync).
// X[b][n][128] f32 -> X2[bp][n][half][128] fp16 (bp=b>>1, half=b&1):
// per (bp,n) 512 contiguous bytes = the 2-batch slice one gather wave reads.
__global__ __launch_bounds__(256)
void k_prep(const float* __restrict__ X, h16x8* __restrict__ X2, int do_repack,
            const int* __restrict__ ei, const float* __restrict__ ew,
            float* deg, int* count,
            const float* __restrict__ attn,
            const float* __restrict__ Wcz, const float* __restrict__ bcz,
            const float* __restrict__ Wlz, const float* __restrict__ blz,
            const float* __restrict__ Wch, const float* __restrict__ bch,
            const float* __restrict__ Wlh, const float* __restrict__ blh,
            float* consts) {
    int gid = blockIdx.x * blockDim.x + threadIdx.x;
    int gsz = gridDim.x * blockDim.x;
    // ---- degree ----
    int stride = ei_stride(ei);
    for (int e = gid; e < NE; e += gsz) {
        int d = ei[(size_t)(NE + e) * stride];
        atomicAdd(&deg[d], ew[e]);
        atomicAdd(&count[d], 1);
    }
    // ---- repack ----
    if (do_repack) {
        const int total = NN * 256;
        for (int i = gid; i < total; i += gsz) {
            int n = i >> 8, t = i & 255;
            int b = t >> 4, chunk = t & 15;
            f32x8 w = ((const f32x8*)X)[((size_t)b * NN + n) * 16 + chunk];
            h16x8 h;
            #pragma unroll
            for (int j = 0; j < 8; ++j) h[j] = (_Float16)w[j];
            X2[((size_t)(b >> 1) * NN + n) * 32 + (b & 1) * 16 + chunk] = h;
        }
    }
    // ---- folded consts (block 0) ----
    if (blockIdx.x == 0) {
        int tid = threadIdx.x;
        {
            int c = tid >> 5, o = tid & 31;
            float mz = 0.f, mh = 0.f;
            for (int k = 0; k < 32; ++k) {
                mz += Wcz[c * 32 + k] * Wlz[k * 32 + o];   // Wl rows 0..31 (H0 half is zero)
                mh += Wch[c * 32 + k] * Wlh[k * 32 + o];
            }
            consts[tid] = mz;
            consts[256 + tid] = mh;
        }
        if (tid < 32) {
            float cz = blz[tid], ch = blh[tid];
            for (int k = 0; k < 32; ++k) {
                cz += bcz[k] * Wlz[k * 32 + tid];
                ch += bch[k] * Wlh[k * 32 + tid];
            }
            consts[512 + tid] = cz;
            consts[544 + tid] = ch;
        }
        if (tid == 0) {
            float a[16], m = -1e30f, s = 0.f;
            for (int t = 0; t < 16; ++t) { a[t] = attn[t]; m = fmaxf(m, a[t]); }
            for (int t = 0; t < 16; ++t) { a[t] = __expf(a[t] - m); s += a[t]; }
            for (int t = 0; t < 16; ++t) consts[576 + t] = a[t] / s;
        }
    }
}

// single block: exclusive scan of count -> offsets/fillptr; dinv = rsqrt(deg+1)
__global__ void k_scan(const float* __restrict__ deg, const int* __restrict__ count,
                       float* dinv, int* offsets, int* fillptr) {
    int tid = threadIdx.x;
    int lane = tid & 63, wv = tid >> 6;
    __shared__ int wsum[16];
    __shared__ int carry;
    if (tid == 0) carry = 0;
    __syncthreads();
    for (int base = 0; base < NN; base += 1024) {
        int i = base + tid;
        int v = (i < NN) ? count[i] : 0;
        int x = v;
        #pragma unroll
        for (int s = 1; s < 64; s <<= 1) {
            int y = __shfl_up(x, s, 64);
            if (lane >= s) x += y;
        }
        if (lane == 63) wsum[wv] = x;
        __syncthreads();
        if (wv == 0 && lane < 16) {
            int y = wsum[lane];
            #pragma unroll
            for (int s = 1; s < 16; s <<= 1) {
                int z = __shfl_up(y, s, 64);
                if (lane >= s) y += z;
            }
            wsum[lane] = y;
        }
        __syncthreads();
        int wbase = (wv == 0) ? 0 : wsum[wv - 1];
        int incl = carry + wbase + x;
        int excl = incl - v;
        if (i < NN) { offsets[i] = excl; fillptr[i] = excl; }
        __syncthreads();
        if (tid == 1023) carry = incl;
        __syncthreads();
    }
    for (int i = tid; i < NN; i += 1024) dinv[i] = rsqrtf(deg[i] + 1.0f);
}

__global__ void k_fill(const int* __restrict__ ei, const float* __restrict__ ew,
                       const float* __restrict__ dinv,
                       int* fillptr, int* csr_src, float* csr_norm) {
    int e = blockIdx.x * blockDim.x + threadIdx.x;
    if (e >= NE) return;
    int stride = ei_stride(ei);
    int s = ei[(size_t)e * stride];
    int d = ei[(size_t)(NE + e) * stride];
    int pos = atomicAdd(&fillptr[d], 1);
    csr_src[pos] = s;
    csr_norm[pos] = dinv[s] * ew[e] * dinv[d];
}

// (1-sigmoid(uz)) * tanh(uh) = (e^{2uh}-1) / ((1+e^{uz})(e^{2uh}+1))
__device__ __forceinline__ float gatefn(float uz, float uh) {
    float ez = __expf(uz);
    float eh = __expf(2.f * uh);
    return (eh - 1.f) * __builtin_amdgcn_rcpf((1.f + ez) * (eh + 1.f));
}

// Batch-partitioned gather, ONE WAVE = ONE NODE:
// lane half (0-31 / 32-63) handles even/odd edges of the same node, so
// cnt/sp/npv are wave-uniform (scalar loads); cross-half shfl_xor folds the
// two edge-partial sums. bp = blockIdx&7 keeps each XCD's working set at
// NN*512B = 5.1MB ~ its private L2.
__global__ __launch_bounds__(256)
void k_main_h(const h16x8* __restrict__ X2,
              const int* __restrict__ offsets, const int* __restrict__ count,
              const float* __restrict__ dinv,
              const int* __restrict__ csr_src, const float* __restrict__ csr_norm,
              const float* __restrict__ consts,
              float* __restrict__ out) {
    __shared__ float sAgg[2 * NT * AGG_LD];   // row = node_in_tile*2 + b_local
    __shared__ float sMz[256], sMh[256], sCz[32], sCh[32], sWs[16];
    int tid = threadIdx.x;
    int bp   = blockIdx.x & 7;
    int tile = blockIdx.x >> 3;

    sMz[tid] = consts[tid];
    sMh[tid] = consts[256 + tid];
    if (tid < 32) { sCz[tid] = consts[512 + tid]; sCh[tid] = consts[544 + tid]; }
    if (tid < 16) sWs[tid] = consts[576 + tid];

    // ---- Phase A ----
    int lane = tid & 63;
    int wv = __builtin_amdgcn_readfirstlane(tid >> 6);   // wave id = node in tile
    int half = lane >> 5;
    int chunk = lane & 31;            // 16B chunk of the 512B (bp,n) slice
    int n = tile * NT + wv;
    const h16x8* xb = X2 + ((size_t)bp * NN) * 32;
    float dn = dinv[n];
    float selfn = (half == 0) ? dn * dn : 0.f;   // count self-loop once
    float acc[8];
    {
        h16x8 w = xb[(size_t)n * 32 + chunk];
        #pragma unroll
        for (int j = 0; j < 8; ++j) acc[j] = selfn * (float)w[j];
    }
    int off = offsets[n], cnt = count[n];        // wave-uniform (scalar)
    const int*   sp  = csr_src + off;
    const float* npv = csr_norm + off;
    int e = 0;
    if (cnt >= 8) {
        int s0 = sp[0], s1 = sp[1], s2 = sp[2], s3 = sp[3];
        int sa = half ? s1 : s0, sb = half ? s3 : s2;
        h16x8 a0 = xb[(size_t)sa * 32 + chunk];
        h16x8 a1 = xb[(size_t)sb * 32 + chunk];
        for (e = 4; e + 4 <= cnt; e += 4) {
            int t0 = sp[e], t1 = sp[e + 1], t2 = sp[e + 2], t3 = sp[e + 3];
            int ta = half ? t1 : t0, tb = half ? t3 : t2;
            h16x8 b0 = xb[(size_t)ta * 32 + chunk];
            h16x8 b1 = xb[(size_t)tb * 32 + chunk];
            __builtin_amdgcn_sched_barrier(0);   // keep b-loads issued before a-consume
            float n0 = npv[e - 4], n1 = npv[e - 3], n2 = npv[e - 2], n3 = npv[e - 1];
            float na = half ? n1 : n0, nb = half ? n3 : n2;
            #pragma unroll
            for (int j = 0; j < 8; ++j) acc[j] += na * (float)a0[j];
            #pragma unroll
            for (int j = 0; j < 8; ++j) acc[j] += nb * (float)a1[j];
            a0 = b0; a1 = b1;
        }
        float n0 = npv[e - 4], n1 = npv[e - 3], n2 = npv[e - 2], n3 = npv[e - 1];
        float na = half ? n1 : n0, nb = half ? n3 : n2;
        #pragma unroll
        for (int j = 0; j < 8; ++j) acc[j] += na * (float)a0[j];
        #pragma unroll
        for (int j = 0; j < 8; ++j) acc[j] += nb * (float)a1[j];
    }
    for (; e + 2 <= cnt; e += 2) {
        int s0 = sp[e], s1 = sp[e + 1];
        int sa = half ? s1 : s0;
        float n0 = npv[e], n1 = npv[e + 1];
        float na = half ? n1 : n0;
        h16x8 w = xb[(size_t)sa * 32 + chunk];
        #pragma unroll
        for (int j = 0; j < 8; ++j) acc[j] += na * (float)w[j];
    }
    if (e < cnt) {
        int s = sp[e];
        float nrm = half ? 0.f : npv[e];
        h16x8 w = xb[(size_t)s * 32 + chunk];
        #pragma unroll
        for (int j = 0; j < 8; ++j) acc[j] += nrm * (float)w[j];
    }
    // fold the two edge-halves
    #pragma unroll
    for (int j = 0; j < 8; ++j) acc[j] += __shfl_xor(acc[j], 32);
    // store (lanes 0..31): acc[j] = A[b_local][c][t], t = (sub&1)*8 + j
    if (lane < 32) {
        int bl = chunk >> 4;
        int sub = chunk & 15;
        int r = wv * 2 + bl;
        int c = sub >> 1;
        int tpb = (sub & 1) * 4;
        float* rowp = &sAgg[r * AGG_LD + c * 2];
        #pragma unroll
        for (int k = 0; k < 4; ++k) {
            f32x2 v = {acc[2 * k], acc[2 * k + 1]};
            *(f32x2*)&rowp[(tpb + k) * 16] = v;
        }
    }
    __syncthreads();

    // ---- Phase B: thread -> one (row, o) output ----
    int o = tid & 31, rr = tid >> 5;     // rr = node_in_tile*2 + b_local
    float mz[8], mh[8];
    #pragma unroll
    for (int c = 0; c < 8; ++c) { mz[c] = sMz[c * 32 + o]; mh[c] = sMh[c * 32 + o]; }
    float czo = sCz[o], cho = sCh[o];
    const f32x4* r0 = (const f32x4*)&sAgg[rr * AGG_LD];
    f32x2 o0 = {0.f, 0.f};
    #pragma unroll
    for (int tp = 0; tp < 8; ++tp) {
        f32x4 A0[4];
        #pragma unroll
        for (int k = 0; k < 4; ++k) A0[k] = r0[tp * 4 + k];
        f32x2 uz = {czo, czo}, uh = {cho, cho};
        #pragma unroll
        for (int k = 0; k < 4; ++k) {
            f32x2 p = A0[k].xy, q = A0[k].zw;
            uz += p * mz[2 * k]; uz += q * mz[2 * k + 1];
            uh += p * mh[2 * k]; uh += q * mh[2 * k + 1];
        }
        f32x2 wsp = {sWs[2 * tp], sWs[2 * tp + 1]};
        f32x2 g;
        g.x = gatefn(uz.x, uh.x);
        g.y = gatefn(uz.y, uh.y);
        o0 += wsp * g;
    }
    int b  = bp * 2 + (rr & 1);
    int n2 = tile * NT + (rr >> 1);
    out[((size_t)b * NN + n2) * 32 + o] = o0.x + o0.y;
}

// f32 fallback path — used only if ws_size is too small for the fp16 repack
__global__ __launch_bounds__(256)
void k_main_f32(const float* __restrict__ X,
                const int* __restrict__ offsets, const int* __restrict__ count,
                const float* __restrict__ dinv,
                const int* __restrict__ csr_src, const float* __restrict__ csr_norm,
                const float* __restrict__ consts,
                float* __restrict__ out) {
    __shared__ float sAgg[NB * 128];
    __shared__ float sMz[256], sMh[256], sCz[32], sCh[32], sWs[16];
    int tid = threadIdx.x;
    int n = blockIdx.x;

    sMz[tid] = consts[tid];
    sMh[tid] = consts[256 + tid];
    if (tid < 32) { sCz[tid] = consts[512 + tid]; sCh[tid] = consts[544 + tid]; }
    if (tid < 16) sWs[tid] = consts[576 + tid];

    int b = tid >> 4, chunk = tid & 15;
    const f32x8* xv = (const f32x8*)X;
    float dn = dinv[n];
    float selfn = dn * dn;
    float acc[8];
    {
        f32x8 w = xv[((size_t)b * NN + n) * 16 + chunk];
        #pragma unroll
        for (int j = 0; j < 8; ++j) acc[j] = selfn * w[j];
    }
    int off = offsets[n], cnt = count[n];
    for (int e = off; e < off + cnt; ++e) {
        int s = csr_src[e];
        float nrm = csr_norm[e];
        f32x8 w = xv[((size_t)b * NN + s) * 16 + chunk];
        #pragma unroll
        for (int j = 0; j < 8; ++j) acc[j] += nrm * w[j];
    }
    #pragma unroll
    for (int j = 0; j < 8; ++j) sAgg[tid * 8 + j] = acc[j];
    __syncthreads();

    int o = tid & 31, b0 = tid >> 5;
    float mz[8], mh[8];
    #pragma unroll
    for (int c = 0; c < 8; ++c) { mz[c] = sMz[c * 32 + o]; mh[c] = sMh[c * 32 + o]; }
    float czo = sCz[o], cho = sCh[o];
    float acc0 = 0.f, acc1 = 0.f;
    #pragma unroll
    for (int t = 0; t < 16; ++t) {
        float uz0 = czo, uh0 = cho, uz1 = czo, uh1 = cho;
        #pragma unroll
        for (int c = 0; c < 8; ++c) {
            float a0 = sAgg[b0 * 128 + c * 16 + t];
            float a1 = sAgg[(b0 + 8) * 128 + c * 16 + t];
            uz0 += a0 * mz[c]; uh0 += a0 * mh[c];
            uz1 += a1 * mz[c]; uh1 += a1 * mh[c];
        }
        float w = sWs[t];
        acc0 += w * gatefn(uz0, uh0);
        acc1 += w * gatefn(uz1, uh1);
    }
    out[((size_t)b0 * NN + n) * 32 + o]       = acc0;
    out[((size_t)(b0 + 8) * NN + n) * 32 + o] = acc1;
}

extern "C" void kernel_launch(void* const* d_in, const int* in_sizes, int n_in,
                              void* d_out, int out_size, void* d_ws, size_t ws_size,
                              hipStream_t stream) {
    const float* X    = (const float*)d_in[0];
    const int*   ei   = (const int*)d_in[1];
    const float* ew   = (const float*)d_in[2];
    const float* attn = (const float*)d_in[3];
    const float* Wcz  = (const float*)d_in[4];
    const float* bcz  = (const float*)d_in[5];
    const float* Wlz  = (const float*)d_in[6];
    const float* blz  = (const float*)d_in[7];
    // d_in[8..11] = Wcr,bcr,Wlr,blr — provably unused (R multiplies H0=0)
    const float* Wch  = (const float*)d_in[12];
    const float* bch  = (const float*)d_in[13];
    const float* Wlh  = (const float*)d_in[14];
    const float* blh  = (const float*)d_in[15];
    float* out = (float*)d_out;

    const size_t x2_bytes = (size_t)NN * 256 * 16;   // 40.96 MB fp16 repack
    const size_t small_bytes = (size_t)NN * 4 * 5 + (size_t)NE * 4 * 2 + 592 * 4;
    bool use_h = (ws_size >= x2_bytes + small_bytes);

    char* p = (char*)d_ws;
    h16x8* X2 = nullptr;
    if (use_h) { X2 = (h16x8*)p; p += x2_bytes; }
    float* deg      = (float*)p; p += NN * 4;
    int*   count    = (int*)p;   p += NN * 4;   // adjacent to deg: one memset
    float* dinv     = (float*)p; p += NN * 4;
    int*   offsets  = (int*)p;   p += NN * 4;
    int*   fillptr  = (int*)p;   p += NN * 4;
    int*   csr_src  = (int*)p;   p += NE * 4;
    float* csr_norm = (float*)p; p += NE * 4;
    float* consts   = (float*)p; p += 592 * 4;

    hipMemsetAsync(deg, 0, (size_t)NN * 8, stream);   // deg + count
    hipLaunchKernelGGL(k_prep, dim3(1280), dim3(256), 0, stream,
                       X, X2, use_h ? 1 : 0, ei, ew, deg, count,
                       attn, Wcz, bcz, Wlz, blz, Wch, bch, Wlh, blh, consts);
    hipLaunchKernelGGL(k_scan, dim3(1), dim3(1024), 0, stream,
                       deg, count, dinv, offsets, fillptr);
    hipLaunchKernelGGL(k_fill, dim3((NE + 255) / 256), dim3(256), 0, stream,
                       ei, ew, dinv, fillptr, csr_src, csr_norm);
    if (use_h) {
        hipLaunchKernelGGL(k_main_h, dim3((NN / NT) * 8), dim3(256), 0, stream,
                           X2, offsets, count, dinv, csr_src, csr_norm, consts, out);
    } else {
        hipLaunchKernelGGL(k_main_f32, dim3(NN), dim3(256), 0, stream,
                           X, offsets, count, dinv, csr_src, csr_norm, consts, out);
    }
}